// Round 14
// baseline (9322.893 us; speedup 1.0000x reference)
//
#include <hip/hip_runtime.h>

typedef unsigned short u16;
typedef unsigned int   u32;
typedef unsigned long long u64;
typedef __attribute__((ext_vector_type(8))) _Float16 f16x8;
typedef __attribute__((ext_vector_type(4))) float    f32x4;

constexpr int SS  = 700;
constexpr int NWG = 39;    // 13 WGs per layer; each WG: 32 j x 64 b

// ---- workspace layout (float offsets) ----
constexpr size_t OA1  = 0;        // A-pack L1 [13 jb][8 wv][13 kt][64 lane][8] f16
constexpr size_t OA2  = 346112;   // A-pack L2 [13][8][25][64][8] f16
constexpr size_t OA3  = 1011712;  // A-pack L3
constexpr size_t OWH  = 1677312;  // head weights (3-block-summed) [121][400] f32
constexpr size_t OBH  = 1725712;  // head biases (pad 128)
constexpr size_t OSBT = 1725840;  // u16 [2 parity][64 b][1200 k]  (h1|h2|h3, f16)
constexpr size_t OBAR = 1802640;  // arrival slots @ +wg*16 (39), gen copies @ +768+lf*16 (16)
constexpr size_t OH3  = 1803696;  // u16 [700 t][64 b][400 j]  (f16)

// ---- output layout (float offsets) ----
constexpr size_t OE   = 0;
constexpr size_t OPI  = 44800;
constexpr size_t OMU1 = 940800;
constexpr size_t OMU2 = 1836800;
constexpr size_t OSG1 = 2732800;
constexpr size_t OSG2 = 3628800;
constexpr size_t ORO  = 4524800;
constexpr size_t OST  = 5420800;

struct Ptrs { const float* p[33]; };

union HU { u16 u; _Float16 h; };

__device__ __forceinline__ u16 f2h(float f) {
  HU c; c.h = (_Float16)f; return c.u;
}
__device__ __forceinline__ float h2f(u16 u) {
  HU c; c.u = u; return (float)c.h;
}

// fast sigmoid/tanh: v_exp_f32 + v_rcp_f32, overflow-safe (rcp(inf)=0)
__device__ __forceinline__ float fsigm(float v) {
  return __builtin_amdgcn_rcpf(1.f + __expf(-v));
}
__device__ __forceinline__ float ftanh(float v) {
  return fmaf(2.f, __builtin_amdgcn_rcpf(1.f + __expf(-2.f * v)), -1.f);
}

__device__ __forceinline__ u32 aload(const u32* p) {
  return __hip_atomic_load(p, __ATOMIC_RELAXED, __HIP_MEMORY_SCOPE_AGENT);
}
__device__ __forceinline__ void astore(u32* p, u32 v) {
  __hip_atomic_store(p, v, __ATOMIC_RELAXED, __HIP_MEMORY_SCOPE_AGENT);
}

// ---------------- setup: pack MFMA A-fragments, init states ----------------
__device__ __forceinline__ float apack_val(const Ptrs& in, int layer, size_t i, int KT)
{
  const int e = (int)(i & 7); const int lane = (int)((i >> 3) & 63);
  size_t q = i >> 9; const int kt = (int)(q % KT); q /= KT;
  const int wv = (int)(q & 7); const int jb = (int)(q >> 3);
  const int rw = lane & 15; const int g = rw & 3; const int jq = rw >> 2;
  const int j = jb * 32 + wv * 4 + jq;
  if (j >= 400) return 0.f;
  const int grow = g * 400 + j;
  const int kk = kt * 32 + 8 * (lane >> 4) + e;
  if (layer == 0) return (kk < 400) ? in.p[8][(size_t)grow * 400 + kk] : 0.f;
  const float* Wih = (layer == 1) ? in.p[11] : in.p[15];
  const float* Whh = (layer == 1) ? in.p[12] : in.p[16];
  return (kk < 400) ? Wih[(size_t)grow * 403 + 3 + kk]
                    : Whh[(size_t)grow * 400 + (kk - 400)];
}

__global__ __launch_bounds__(256) void setup_kernel(Ptrs in, float* __restrict__ ws)
{
  u16* wsu = (u16*)ws;
  const size_t TOTAL = 3481001;
  for (size_t idx = (size_t)blockIdx.x * 256 + threadIdx.x; idx < TOTAL;
       idx += (size_t)gridDim.x * 256) {
    size_t i = idx;
    if (i < 692224)  { wsu[OA1 * 2 + i] = f2h(apack_val(in, 0, i, 13)); continue; }
    i -= 692224;
    if (i < 1331200) { wsu[OA2 * 2 + i] = f2h(apack_val(in, 1, i, 25)); continue; }
    i -= 1331200;
    if (i < 1331200) { wsu[OA3 * 2 + i] = f2h(apack_val(in, 2, i, 25)); continue; }
    i -= 1331200;
    if (i < 48400) {                         // head weights: sum 3 400-blocks
      const int o = (int)(i / 400), k = (int)(i % 400);
      int src, row;
      if      (o == 0)  { src = 19; row = 0; }
      else if (o < 21)  { src = 21; row = o - 1; }
      else if (o < 41)  { src = 23; row = o - 21; }
      else if (o < 61)  { src = 25; row = o - 41; }
      else if (o < 81)  { src = 27; row = o - 61; }
      else if (o < 101) { src = 29; row = o - 81; }
      else              { src = 31; row = o - 101; }
      const float* W = in.p[src] + (size_t)row * 1200;
      ws[OWH + i] = W[k] + W[400 + k] + W[800 + k];
      continue;
    }
    i -= 48400;
    if (i < 121) {                           // head biases
      const int o = (int)i;
      int src, row;
      if      (o == 0)  { src = 20; row = 0; }
      else if (o < 21)  { src = 22; row = o - 1; }
      else if (o < 41)  { src = 24; row = o - 21; }
      else if (o < 61)  { src = 26; row = o - 41; }
      else if (o < 81)  { src = 28; row = o - 61; }
      else if (o < 101) { src = 30; row = o - 81; }
      else              { src = 32; row = o - 101; }
      ws[OBH + i] = in.p[src][row];
      continue;
    }
    i -= 121;
    if (i < 76800) {                         // initial h states -> SBT (f16)
      const int cell = (int)(i / 25600);
      const int rr = (int)(i % 25600);
      const int j = rr >> 6, b = rr & 63;
      const int par = (cell == 1) ? 0 : 1;   // h1->p1, h2->p0, h3->p1
      wsu[OSBT * 2 + (size_t)par * 76800 + (size_t)b * 1200 + cell * 400 + j] =
          f2h(in.p[1 + cell * 2][(size_t)b * 400 + j]);
      continue;
    }
    i -= 76800;
    if (i < 1056) ((u32*)(ws + OBAR))[i] = 0u;
  }
}

// ------------- grid barrier: zero-RMW master-poll, monotone counters -------------
// Arrival: each WG STORES tick n+1 to its own slot (no RMW -> no convoys).
// WG 0's wave 0 gather-polls the 39 slots (one lane each, s_sleep backoff), then
// 16 lanes store the 16 replicated gen copies in parallel. Other WGs poll their
// own gen copy (<=3 pollers/line). Monotone values, no resets, no HW fences
// (data path is MALL-bypass atomics; __syncthreads drains vmcnt before arrival).
__device__ __forceinline__ void grid_barrier(u32* bar, int n)
{
  __syncthreads();                       // drains publish stores of all waves
  if (threadIdx.x == 0)
    astore(bar + (size_t)blockIdx.x * 16, (u32)(n + 1));
  if (blockIdx.x == 0) {
    if (threadIdx.x < 64) {
      const int idx = ((int)threadIdx.x < NWG) ? (int)threadIdx.x : 0;
      const u32* cp = bar + (size_t)idx * 16;
      while (__ballot(aload(cp) >= (u32)(n + 1)) != ~0ull)
        __builtin_amdgcn_s_sleep(1);
      if (threadIdx.x < 16)
        astore(bar + 768 + (size_t)threadIdx.x * 16, (u32)(n + 1));
    }
  } else if (threadIdx.x == 0) {
    const u32* gen = bar + 768 + (size_t)(blockIdx.x & 15) * 16;
    while (aload(gen) < (u32)(n + 1))
      __builtin_amdgcn_s_sleep(1);
    __atomic_signal_fence(__ATOMIC_SEQ_CST);
  }
  __syncthreads();
}

// ---------------- scan body ----------------
template<int LAYER>
__device__ __forceinline__ void scan_body(Ptrs in, float* __restrict__ ws,
                                          float* __restrict__ out, char* __restrict__ lds)
{
  constexpr int KT   = (LAYER == 0) ? 13 : 25;     // K tiles of 32 (L1 padded 400->416)
  constexpr int RB   = KT * 64 + 16;               // LDS row bytes (+8 f16 pad)
  constexpr int CH   = KT * 8;                     // u64 chunks per row (104 / 200)
  constexpr int COL0 = (LAYER == 2) ? 400 : 0;     // SBT col origin (f16 idx)
  constexpr int WCOL = LAYER * 400;                // write col base
  constexpr size_t OA = (LAYER == 0) ? OA1 : ((LAYER == 1) ? OA2 : OA3);

  const int jb   = (int)blockIdx.x - 13 * LAYER;
  const int tid  = (int)threadIdx.x;
  const int lane = tid & 63;
  const int wv   = tid >> 6;          // 0..7 : j-quad owner
  const int jq   = lane >> 4;         // 0..3
  const int bcol = lane & 15;

  u16* SBT = (u16*)(ws + OSBT);
  u32* H3w = (u32*)(ws + OH3);
  u32* bar = (u32*)(ws + OBAR);
  const float* x = in.p[0];

  const int j = jb * 32 + wv * 4 + jq;
  const bool jok = (j < 400);

  // finalize constants (per-lane)
  float xw[12], bias[4], cr[4];
  {
    const float* Wx = (LAYER == 0) ? in.p[7]  : ((LAYER == 1) ? in.p[11] : in.p[15]);
    const int    xs = (LAYER == 0) ? 3 : 403;
    const float* b0 = (LAYER == 0) ? in.p[9]  : ((LAYER == 1) ? in.p[13] : in.p[17]);
    const float* b1 = (LAYER == 0) ? in.p[10] : ((LAYER == 1) ? in.p[14] : in.p[18]);
    const float* ci = (LAYER == 0) ? in.p[2]  : ((LAYER == 1) ? in.p[4]  : in.p[6]);
#pragma unroll
    for (int g = 0; g < 4; ++g) {
      const int grow = g * 400 + j;
#pragma unroll
      for (int dk = 0; dk < 3; ++dk)
        xw[g * 3 + dk] = jok ? Wx[(size_t)grow * xs + dk] : 0.f;
      bias[g] = jok ? (b0[grow] + b1[grow]) : 0.f;
    }
#pragma unroll
    for (int bt = 0; bt < 4; ++bt)
      cr[bt] = jok ? ci[(size_t)(bt * 16 + bcol) * 400 + j] : 0.f;
  }

  // A-fragments (weights) -> registers, resident for the whole scan
  f16x8 A[KT];
  {
    const u16* ap = (u16*)ws + OA * 2 + ((size_t)(jb * 8 + wv) * KT * 64 + lane) * 8;
#pragma unroll
    for (int kt = 0; kt < KT; ++kt)
      A[kt] = *(const f16x8*)(ap + (size_t)kt * 512);
  }

  for (int n = 0; n < 702; ++n) {
    const int p = n & 1;
    const int t = n - LAYER;
    const bool active = (t >= 0) && (t < SS);
    float xv[12];
    if (active) {
#pragma unroll
      for (int bt = 0; bt < 4; ++bt) {
        const float* xp = x + (size_t)t * 192 + (bt * 16 + bcol) * 3;
        xv[bt * 3] = xp[0]; xv[bt * 3 + 1] = xp[1]; xv[bt * 3 + 2] = xp[2];
      }
      // stage h: MALL-bypass u64 atomic loads -> LDS, 2 deep rounds (13 + 12)
      const u64* src = (const u64*)(SBT + (size_t)(p ^ 1) * 76800 + COL0);  // row = 300 u64
      {
        u64 tv[13];
#pragma unroll
        for (int i = 0; i < 13; ++i) {
          const int c = tid + i * 512;
          tv[i] = __hip_atomic_load(src + (size_t)(c / CH) * 300 + (c % CH),
                                    __ATOMIC_RELAXED, __HIP_MEMORY_SCOPE_AGENT);
        }
#pragma unroll
        for (int i = 0; i < 13; ++i) {
          const int c = tid + i * 512;
          *(u64*)(lds + (size_t)(c / CH) * RB + (size_t)(c % CH) * 8) = tv[i];
        }
      }
      if constexpr (KT == 25) {
        u64 tw[12];
#pragma unroll
        for (int i = 0; i < 12; ++i) {
          const int c = tid + (13 + i) * 512;
          tw[i] = __hip_atomic_load(src + (size_t)(c / CH) * 300 + (c % CH),
                                    __ATOMIC_RELAXED, __HIP_MEMORY_SCOPE_AGENT);
        }
#pragma unroll
        for (int i = 0; i < 12; ++i) {
          const int c = tid + (13 + i) * 512;
          *(u64*)(lds + (size_t)(c / CH) * RB + (size_t)(c % CH) * 8) = tw[i];
        }
      }
    }
    __syncthreads();
    if (active) {
      f32x4 acc[4];
#pragma unroll
      for (int bt = 0; bt < 4; ++bt) acc[bt] = (f32x4){0.f, 0.f, 0.f, 0.f};
#pragma unroll
      for (int kt = 0; kt < KT; ++kt) {
#pragma unroll
        for (int bt = 0; bt < 4; ++bt) {
          const f16x8 bv = *(const f16x8*)(lds + (size_t)(bt * 16 + bcol) * RB
                                               + jq * 16 + kt * 64);
          acc[bt] = __builtin_amdgcn_mfma_f32_16x16x32_f16(A[kt], bv, acc[bt], 0, 0, 0);
        }
      }
#pragma unroll
      for (int bt = 0; bt < 4; ++bt) {
        const int b = bt * 16 + bcol;
        float gv[4];
#pragma unroll
        for (int g = 0; g < 4; ++g)
          gv[g] = acc[bt][g] + bias[g] + xv[bt * 3] * xw[g * 3]
                + xv[bt * 3 + 1] * xw[g * 3 + 1] + xv[bt * 3 + 2] * xw[g * 3 + 2];
        const float fi = fsigm(gv[0]), ff = fsigm(gv[1]);
        const float gg = ftanh(gv[2]), oo = fsigm(gv[3]);
        const float cn = ff * cr[bt] + fi * gg;
        const float hn = oo * ftanh(cn);
        cr[bt] = cn;
        // pack (j, j+1) via shfl_xor(16) and publish directly (no LDS round-trip)
        const u32 own  = f2h(hn);
        const u32 part = (u32)__shfl_xor((int)own, 16, 64);
        if (((lane >> 4) & 1) == 0 && jok) {
          const u32 w = own | (part << 16);
          __hip_atomic_store((u32*)SBT + (size_t)p * 38400 + (size_t)b * 600
                                 + ((WCOL + j) >> 1),
                             w, __ATOMIC_RELAXED, __HIP_MEMORY_SCOPE_AGENT);
          if (LAYER == 2) H3w[(((size_t)t * 64 + b) * 400 + j) >> 1] = w;
        }
        if (jok && t == SS - 1) {
          out[OST + (size_t)(LAYER * 2) * 25600     + (size_t)b * 400 + j] = hn;
          out[OST + (size_t)(LAYER * 2 + 1) * 25600 + (size_t)b * 400 + j] = cn;
        }
      }
    }
    if (n < 701) grid_barrier(bar, n);
  }
}

// Normal launch: 39 WGs on 256 CUs are always co-resident (1 WG/CU, LDS-limited).
__global__ __launch_bounds__(512, 2) void lstm_scan(Ptrs in, float* __restrict__ ws,
                                                    float* __restrict__ out)
{
  __shared__ __align__(16) char lds[103424];   // 64 rows x 1616 B (L1 uses 54272)
  if (blockIdx.x < 13)      scan_body<0>(in, ws, out, lds);
  else if (blockIdx.x < 26) scan_body<1>(in, ws, out, lds);
  else                      scan_body<2>(in, ws, out, lds);
}

// ---------------- MDN heads ----------------
__device__ __forceinline__ void dot2(const u16* hr,
    const float* __restrict__ w0p, const float* __restrict__ w1p,
    float b0, float b1, float& r0, float& r1)
{
  float a0 = b0, a1 = b1;
  const float2* W0 = (const float2*)w0p;
  const float2* W1 = (const float2*)w1p;
#pragma unroll 2
  for (int m = 0; m < 200; ++m) {
    const u32 u = *(const u32*)(hr + 2 * m);
    const float lo = h2f((u16)(u & 0xffffu));
    const float hi = h2f((u16)(u >> 16));
    const float2 c0 = W0[m], c1 = W1[m];
    a0 = fmaf(hi, c0.y, fmaf(lo, c0.x, a0));
    a1 = fmaf(hi, c1.y, fmaf(lo, c1.x, a1));
  }
  r0 = a0; r1 = a1;
}

__device__ __forceinline__ float dot1(const u16* hr, const float* __restrict__ w0p, float b0)
{
  float a0 = b0;
  const float2* W0 = (const float2*)w0p;
#pragma unroll 2
  for (int m = 0; m < 200; ++m) {
    const u32 u = *(const u32*)(hr + 2 * m);
    a0 = fmaf(h2f((u16)(u >> 16)),     W0[m].y,
         fmaf(h2f((u16)(u & 0xffffu)), W0[m].x, a0));
  }
  return a0;
}

__global__ __launch_bounds__(256) void heads_kernel(const float* __restrict__ ws,
                                                    float* __restrict__ out)
{
  __shared__ u16 hs[64 * 402];                 // dword stride 201 -> conflict-free
  const u16*  H3 = (const u16*)(ws + OH3);
  const float* Wh = ws + OWH;
  const float* bh = ws + OBH;
  const int s = blockIdx.x;
  const int tid = threadIdx.x;
  {
    const u32* H3r = (const u32*)(H3 + (size_t)s * 25600);   // [b][400 j] rows
    u32* hs32 = (u32*)hs;
    for (int idx = tid; idx < 64 * 200; idx += 256) {
      const int bb = idx / 200, cc = idx % 200;
      hs32[bb * 201 + cc] = H3r[bb * 200 + cc];
    }
  }
  __syncthreads();
  const int wv = tid >> 6, lane = tid & 63;
  const u16* hr = hs + lane * 402;
  const size_t bs700 = (size_t)lane * 700 + s;

  if (wv == 0) {
    out[OE + bs700] = 1.f / (1.f + expf(dot1(hr, Wh, bh[0])));
    float pl[20];
#pragma unroll
    for (int op = 0; op < 10; ++op) {
      float r0, r1;
      dot2(hr, Wh + (size_t)(1 + 2 * op) * 400, Wh + (size_t)(2 + 2 * op) * 400,
           bh[1 + 2 * op], bh[2 + 2 * op], r0, r1);
      pl[2 * op] = r0; pl[2 * op + 1] = r1;
    }
    float mx = pl[0];
#pragma unroll
    for (int i = 1; i < 20; ++i) mx = fmaxf(mx, pl[i]);
    float sm = 0.f;
#pragma unroll
    for (int i = 0; i < 20; ++i) { pl[i] = expf(pl[i] - mx); sm += pl[i]; }
    const float inv = 1.f / sm;
    float* po = out + OPI + bs700 * 20;
#pragma unroll
    for (int i = 0; i < 20; ++i) po[i] = pl[i] * inv;
  } else if (wv == 1) {
    for (int op = 0; op < 20; ++op) {
      float r0, r1;
      dot2(hr, Wh + (size_t)(21 + 2 * op) * 400, Wh + (size_t)(22 + 2 * op) * 400,
           bh[21 + 2 * op], bh[22 + 2 * op], r0, r1);
      const int o0 = 2 * op, o1 = o0 + 1;
      out[(o0 < 20) ? (OMU1 + bs700 * 20 + o0) : (OMU2 + bs700 * 20 + o0 - 20)] = r0;
      out[(o1 < 20) ? (OMU1 + bs700 * 20 + o1) : (OMU2 + bs700 * 20 + o1 - 20)] = r1;
    }
  } else if (wv == 2) {
    for (int op = 0; op < 20; ++op) {
      float r0, r1;
      dot2(hr, Wh + (size_t)(61 + 2 * op) * 400, Wh + (size_t)(62 + 2 * op) * 400,
           bh[61 + 2 * op], bh[62 + 2 * op], r0, r1);
      const int o0 = 2 * op, o1 = o0 + 1;
      out[(o0 < 20) ? (OSG1 + bs700 * 20 + o0) : (OSG2 + bs700 * 20 + o0 - 20)] = expf(r0);
      out[(o1 < 20) ? (OSG1 + bs700 * 20 + o1) : (OSG2 + bs700 * 20 + o1 - 20)] = expf(r1);
    }
  } else {
    for (int op = 0; op < 10; ++op) {
      float r0, r1;
      dot2(hr, Wh + (size_t)(101 + 2 * op) * 400, Wh + (size_t)(102 + 2 * op) * 400,
           bh[101 + 2 * op], bh[102 + 2 * op], r0, r1);
      float* po = out + ORO + bs700 * 20;
      po[2 * op] = tanhf(r0); po[2 * op + 1] = tanhf(r1);
    }
  }
}

// ---------------- launch ----------------
extern "C" void kernel_launch(void* const* d_in, const int* in_sizes, int n_in,
                              void* d_out, int out_size, void* d_ws, size_t ws_size,
                              hipStream_t stream)
{
  Ptrs in;
  for (int i = 0; i < 33; ++i) in.p[i] = (const float*)d_in[i];
  float* ws  = (float*)d_ws;
  float* out = (float*)d_out;

  hipLaunchKernelGGL(setup_kernel, dim3(4096), dim3(256), 0, stream, in, ws);
  hipLaunchKernelGGL(lstm_scan, dim3(NWG), dim3(512), 0, stream, in, ws, out);
  hipLaunchKernelGGL(heads_kernel, dim3(SS), dim3(256), 0, stream, (const float*)ws, out);
}

// Round 15
// 8106.982 us; speedup vs baseline: 1.1500x; 1.1500x over previous
//
#include <hip/hip_runtime.h>

typedef unsigned short u16;
typedef unsigned int   u32;
typedef unsigned long long u64;
typedef __attribute__((ext_vector_type(8))) _Float16 f16x8;
typedef __attribute__((ext_vector_type(4))) float    f32x4;

constexpr int SS  = 700;
constexpr int NWG = 39;    // 13 WGs per layer; each WG: 32 j x 64 b

// ---- workspace layout (float offsets) ----
constexpr size_t OA1  = 0;        // A-pack L1 [13 jb][8 wv][13 kt][64 lane][8] f16
constexpr size_t OA2  = 346112;   // A-pack L2 [13][8][25][64][8] f16
constexpr size_t OA3  = 1011712;  // A-pack L3
constexpr size_t OWH  = 1677312;  // head weights (3-block-summed) [121][400] f32
constexpr size_t OBH  = 1725712;  // head biases (pad 128)
constexpr size_t OSBT = 1725840;  // u16 [2 parity][64 b][1200 k]  (h1|h2|h3, f16)
constexpr size_t OBAR = 1802640;  // barrier: 16 leaves @ +lf*32, root @512, gen copies @544+lf*32
constexpr size_t OH3  = 1803696;  // u16 [700 t][64 b][400 j]  (f16)

// ---- output layout (float offsets) ----
constexpr size_t OE   = 0;
constexpr size_t OPI  = 44800;
constexpr size_t OMU1 = 940800;
constexpr size_t OMU2 = 1836800;
constexpr size_t OSG1 = 2732800;
constexpr size_t OSG2 = 3628800;
constexpr size_t ORO  = 4524800;
constexpr size_t OST  = 5420800;

struct Ptrs { const float* p[33]; };

union HU { u16 u; _Float16 h; };

__device__ __forceinline__ u16 f2h(float f) {
  HU c; c.h = (_Float16)f; return c.u;
}
__device__ __forceinline__ float h2f(u16 u) {
  HU c; c.u = u; return (float)c.h;
}

// fast sigmoid/tanh: v_exp_f32 + v_rcp_f32, overflow-safe (rcp(inf)=0)
__device__ __forceinline__ float fsigm(float v) {
  return __builtin_amdgcn_rcpf(1.f + __expf(-v));
}
__device__ __forceinline__ float ftanh(float v) {
  return fmaf(2.f, __builtin_amdgcn_rcpf(1.f + __expf(-2.f * v)), -1.f);
}

__device__ __forceinline__ float sigm(float v) { return 1.f / (1.f + expf(-v)); }

// ---------------- setup: pack MFMA A-fragments, init states ----------------
__device__ __forceinline__ float apack_val(const Ptrs& in, int layer, size_t i, int KT)
{
  const int e = (int)(i & 7); const int lane = (int)((i >> 3) & 63);
  size_t q = i >> 9; const int kt = (int)(q % KT); q /= KT;
  const int wv = (int)(q & 7); const int jb = (int)(q >> 3);
  const int rw = lane & 15; const int g = rw & 3; const int jq = rw >> 2;
  const int j = jb * 32 + wv * 4 + jq;
  if (j >= 400) return 0.f;
  const int grow = g * 400 + j;
  const int kk = kt * 32 + 8 * (lane >> 4) + e;
  if (layer == 0) return (kk < 400) ? in.p[8][(size_t)grow * 400 + kk] : 0.f;
  const float* Wih = (layer == 1) ? in.p[11] : in.p[15];
  const float* Whh = (layer == 1) ? in.p[12] : in.p[16];
  return (kk < 400) ? Wih[(size_t)grow * 403 + 3 + kk]
                    : Whh[(size_t)grow * 400 + (kk - 400)];
}

__global__ __launch_bounds__(256) void setup_kernel(Ptrs in, float* __restrict__ ws)
{
  u16* wsu = (u16*)ws;
  const size_t TOTAL = 3481001;
  for (size_t idx = (size_t)blockIdx.x * 256 + threadIdx.x; idx < TOTAL;
       idx += (size_t)gridDim.x * 256) {
    size_t i = idx;
    if (i < 692224)  { wsu[OA1 * 2 + i] = f2h(apack_val(in, 0, i, 13)); continue; }
    i -= 692224;
    if (i < 1331200) { wsu[OA2 * 2 + i] = f2h(apack_val(in, 1, i, 25)); continue; }
    i -= 1331200;
    if (i < 1331200) { wsu[OA3 * 2 + i] = f2h(apack_val(in, 2, i, 25)); continue; }
    i -= 1331200;
    if (i < 48400) {                         // head weights: sum 3 400-blocks
      const int o = (int)(i / 400), k = (int)(i % 400);
      int src, row;
      if      (o == 0)  { src = 19; row = 0; }
      else if (o < 21)  { src = 21; row = o - 1; }
      else if (o < 41)  { src = 23; row = o - 21; }
      else if (o < 61)  { src = 25; row = o - 41; }
      else if (o < 81)  { src = 27; row = o - 61; }
      else if (o < 101) { src = 29; row = o - 81; }
      else              { src = 31; row = o - 101; }
      const float* W = in.p[src] + (size_t)row * 1200;
      ws[OWH + i] = W[k] + W[400 + k] + W[800 + k];
      continue;
    }
    i -= 48400;
    if (i < 121) {                           // head biases
      const int o = (int)i;
      int src, row;
      if      (o == 0)  { src = 20; row = 0; }
      else if (o < 21)  { src = 22; row = o - 1; }
      else if (o < 41)  { src = 24; row = o - 21; }
      else if (o < 61)  { src = 26; row = o - 41; }
      else if (o < 81)  { src = 28; row = o - 61; }
      else if (o < 101) { src = 30; row = o - 81; }
      else              { src = 32; row = o - 101; }
      ws[OBH + i] = in.p[src][row];
      continue;
    }
    i -= 121;
    if (i < 76800) {                         // initial h states -> SBT (f16)
      const int cell = (int)(i / 25600);
      const int rr = (int)(i % 25600);
      const int j = rr >> 6, b = rr & 63;
      const int par = (cell == 1) ? 0 : 1;   // h1->p1, h2->p0, h3->p1
      wsu[OSBT * 2 + (size_t)par * 76800 + (size_t)b * 1200 + cell * 400 + j] =
          f2h(in.p[1 + cell * 2][(size_t)b * 400 + j]);
      continue;
    }
    i -= 76800;
    if (i < 1056) ((u32*)(ws + OBAR))[i] = 0u;
  }
}

// ---------------- grid barrier: 16-leaf tree + 16-way replicated gen ----------------
// 39 WGs: leaves 0..6 have 3 members (thr=2), leaves 7..15 have 2 (thr=1).
// Each WG polls its OWN gen copy (<=3 pollers per line) -> no MALL line contention.
// Data path is MALL-bypass atomics; __syncthreads drains vmcnt -> no HW fences.
__device__ __forceinline__ void grid_barrier(u32* bar)
{
  __syncthreads();
  if (threadIdx.x == 0) {
    const int lf = (int)(blockIdx.x & 15);
    u32* leaf = bar + lf * 32;
    u32* root = bar + 512;
    u32* gen  = bar + 544 + lf * 32;
    const u32 thr = (lf < 7) ? 2u : 1u;
    const u32 g = __hip_atomic_load(gen, __ATOMIC_RELAXED, __HIP_MEMORY_SCOPE_AGENT);
    __atomic_signal_fence(__ATOMIC_SEQ_CST);
    const u32 lo = __hip_atomic_fetch_add(leaf, 1u, __ATOMIC_RELAXED, __HIP_MEMORY_SCOPE_AGENT);
    if (lo == thr) {
      __hip_atomic_store(leaf, 0u, __ATOMIC_RELAXED, __HIP_MEMORY_SCOPE_AGENT);
      const u32 ro = __hip_atomic_fetch_add(root, 1u, __ATOMIC_RELAXED, __HIP_MEMORY_SCOPE_AGENT);
      if (ro == 15u) {
        __hip_atomic_store(root, 0u, __ATOMIC_RELAXED, __HIP_MEMORY_SCOPE_AGENT);
#pragma unroll
        for (int i2 = 0; i2 < 16; ++i2)
          __hip_atomic_store(bar + 544 + i2 * 32, g + 1u, __ATOMIC_RELAXED,
                             __HIP_MEMORY_SCOPE_AGENT);
      }
    }
    while (__hip_atomic_load(gen, __ATOMIC_RELAXED, __HIP_MEMORY_SCOPE_AGENT) == g)
      __builtin_amdgcn_s_sleep(1);
    __atomic_signal_fence(__ATOMIC_SEQ_CST);
  }
  __syncthreads();
}

// ---------------- scan body ----------------
template<int LAYER>
__device__ __forceinline__ void scan_body(Ptrs in, float* __restrict__ ws,
                                          float* __restrict__ out, char* __restrict__ lds,
                                          u16 (*hstage)[32])
{
  constexpr int KT   = (LAYER == 0) ? 13 : 25;     // K tiles of 32 (L1 padded 400->416)
  constexpr int RB   = KT * 64 + 16;               // LDS row bytes (+8 f16 pad)
  constexpr int CH   = KT * 8;                     // u64 chunks per row (104 / 200)
  constexpr int COL0 = (LAYER == 2) ? 400 : 0;     // SBT col origin (f16 idx)
  constexpr int WCOL = LAYER * 400;                // write col base
  constexpr size_t OA = (LAYER == 0) ? OA1 : ((LAYER == 1) ? OA2 : OA3);

  const int jb   = (int)blockIdx.x - 13 * LAYER;
  const int tid  = (int)threadIdx.x;
  const int lane = tid & 63;
  const int wv   = tid >> 6;          // 0..7 : j-quad owner
  const int jq   = lane >> 4;         // 0..3
  const int bcol = lane & 15;

  u16* SBT = (u16*)(ws + OSBT);
  u16* H3  = (u16*)(ws + OH3);
  u32* bar = (u32*)(ws + OBAR);
  const float* x = in.p[0];

  const int j = jb * 32 + wv * 4 + jq;
  const bool jok = (j < 400);

  // finalize constants (per-lane)
  float xw[12], bias[4], cr[4];
  {
    const float* Wx = (LAYER == 0) ? in.p[7]  : ((LAYER == 1) ? in.p[11] : in.p[15]);
    const int    xs = (LAYER == 0) ? 3 : 403;
    const float* b0 = (LAYER == 0) ? in.p[9]  : ((LAYER == 1) ? in.p[13] : in.p[17]);
    const float* b1 = (LAYER == 0) ? in.p[10] : ((LAYER == 1) ? in.p[14] : in.p[18]);
    const float* ci = (LAYER == 0) ? in.p[2]  : ((LAYER == 1) ? in.p[4]  : in.p[6]);
#pragma unroll
    for (int g = 0; g < 4; ++g) {
      const int grow = g * 400 + j;
#pragma unroll
      for (int dk = 0; dk < 3; ++dk)
        xw[g * 3 + dk] = jok ? Wx[(size_t)grow * xs + dk] : 0.f;
      bias[g] = jok ? (b0[grow] + b1[grow]) : 0.f;
    }
#pragma unroll
    for (int bt = 0; bt < 4; ++bt)
      cr[bt] = jok ? ci[(size_t)(bt * 16 + bcol) * 400 + j] : 0.f;
  }

  // A-fragments (weights) -> registers, resident for the whole scan
  f16x8 A[KT];
  {
    const u16* ap = (u16*)ws + OA * 2 + ((size_t)(jb * 8 + wv) * KT * 64 + lane) * 8;
#pragma unroll
    for (int kt = 0; kt < KT; ++kt)
      A[kt] = *(const f16x8*)(ap + (size_t)kt * 512);
  }

  for (int n = 0; n < 702; ++n) {
    const int p = n & 1;
    const int t = n - LAYER;
    const bool active = (t >= 0) && (t < SS);
    float xv[12];
    if (active) {
#pragma unroll
      for (int bt = 0; bt < 4; ++bt) {
        const float* xp = x + (size_t)t * 192 + (bt * 16 + bcol) * 3;
        xv[bt * 3] = xp[0]; xv[bt * 3 + 1] = xp[1]; xv[bt * 3 + 2] = xp[2];
      }
      // stage h: MALL-bypass u64 atomic loads -> LDS, 2 deep rounds (13 + 12)
      // (vs R13's 5 rounds of 5: each round pays one serialized MALL latency)
      const u64* src = (const u64*)(SBT + (size_t)(p ^ 1) * 76800 + COL0);  // row = 300 u64
      {
        u64 tv[13];
#pragma unroll
        for (int i = 0; i < 13; ++i) {
          const int c = tid + i * 512;
          tv[i] = __hip_atomic_load(src + (size_t)(c / CH) * 300 + (c % CH),
                                    __ATOMIC_RELAXED, __HIP_MEMORY_SCOPE_AGENT);
        }
#pragma unroll
        for (int i = 0; i < 13; ++i) {
          const int c = tid + i * 512;
          *(u64*)(lds + (size_t)(c / CH) * RB + (size_t)(c % CH) * 8) = tv[i];
        }
      }
      if constexpr (KT == 25) {
        u64 tw[12];
#pragma unroll
        for (int i = 0; i < 12; ++i) {
          const int c = tid + (13 + i) * 512;
          tw[i] = __hip_atomic_load(src + (size_t)(c / CH) * 300 + (c % CH),
                                    __ATOMIC_RELAXED, __HIP_MEMORY_SCOPE_AGENT);
        }
#pragma unroll
        for (int i = 0; i < 12; ++i) {
          const int c = tid + (13 + i) * 512;
          *(u64*)(lds + (size_t)(c / CH) * RB + (size_t)(c % CH) * 8) = tw[i];
        }
      }
    }
    __syncthreads();
    if (active) {
      f32x4 acc[4];
#pragma unroll
      for (int bt = 0; bt < 4; ++bt) acc[bt] = (f32x4){0.f, 0.f, 0.f, 0.f};
#pragma unroll
      for (int kt = 0; kt < KT; ++kt) {
#pragma unroll
        for (int bt = 0; bt < 4; ++bt) {
          const f16x8 bv = *(const f16x8*)(lds + (size_t)(bt * 16 + bcol) * RB
                                               + jq * 16 + kt * 64);
          acc[bt] = __builtin_amdgcn_mfma_f32_16x16x32_f16(A[kt], bv, acc[bt], 0, 0, 0);
        }
      }
      if (jok) {
#pragma unroll
        for (int bt = 0; bt < 4; ++bt) {
          const int b = bt * 16 + bcol;
          float gv[4];
#pragma unroll
          for (int g = 0; g < 4; ++g)
            gv[g] = acc[bt][g] + bias[g] + xv[bt * 3] * xw[g * 3]
                  + xv[bt * 3 + 1] * xw[g * 3 + 1] + xv[bt * 3 + 2] * xw[g * 3 + 2];
          const float fi = fsigm(gv[0]), ff = fsigm(gv[1]);
          const float gg = ftanh(gv[2]), oo = fsigm(gv[3]);
          const float cn = ff * cr[bt] + fi * gg;
          const float hn = oo * ftanh(cn);
          cr[bt] = cn;
          hstage[b][wv * 4 + jq] = f2h(hn);             // pack via LDS (contiguous publish)
          if (LAYER == 2) H3[((size_t)t * 64 + b) * 400 + j] = f2h(hn);
          if (t == SS - 1) {
            out[OST + (size_t)(LAYER * 2) * 25600     + (size_t)b * 400 + j] = hn;
            out[OST + (size_t)(LAYER * 2 + 1) * 25600 + (size_t)b * 400 + j] = cn;
          }
        }
      }
    }
    __syncthreads();
    if (active) {
      // publish h-slice: 2 MALL-bypass u32 atomic stores per thread (2 f16 each),
      // consecutive threads -> consecutive dwords (contiguous 64B runs per b-row)
      const u32* hs32 = (const u32*)hstage;
      for (int c = tid; c < 1024; c += 512) {
        const int b = c >> 4, jp = c & 15;
        if (jb * 32 + jp * 2 < 400)
          __hip_atomic_store((u32*)SBT + (size_t)p * 38400 + (size_t)b * 600
                                 + (WCOL + jb * 32) / 2 + jp,
                             hs32[c], __ATOMIC_RELAXED, __HIP_MEMORY_SCOPE_AGENT);
      }
    }
    grid_barrier(bar);
  }
}

// Normal launch: 39 WGs on 256 CUs are always co-resident (1 WG/CU, LDS-limited).
__global__ __launch_bounds__(512, 2) void lstm_scan(Ptrs in, float* __restrict__ ws,
                                                    float* __restrict__ out)
{
  __shared__ __align__(16) char lds[103424];   // 64 rows x 1616 B (L1 uses 54272)
  __shared__ u16 hstage[64][32];               // h repack for paired u32 stores
  if (blockIdx.x < 13)      scan_body<0>(in, ws, out, lds, hstage);
  else if (blockIdx.x < 26) scan_body<1>(in, ws, out, lds, hstage);
  else                      scan_body<2>(in, ws, out, lds, hstage);
}

// ---------------- MDN heads ----------------
__device__ __forceinline__ void dot2(const u16* hr,
    const float* __restrict__ w0p, const float* __restrict__ w1p,
    float b0, float b1, float& r0, float& r1)
{
  float a0 = b0, a1 = b1;
  const float2* W0 = (const float2*)w0p;
  const float2* W1 = (const float2*)w1p;
#pragma unroll 2
  for (int m = 0; m < 200; ++m) {
    const u32 u = *(const u32*)(hr + 2 * m);
    const float lo = h2f((u16)(u & 0xffffu));
    const float hi = h2f((u16)(u >> 16));
    const float2 c0 = W0[m], c1 = W1[m];
    a0 = fmaf(hi, c0.y, fmaf(lo, c0.x, a0));
    a1 = fmaf(hi, c1.y, fmaf(lo, c1.x, a1));
  }
  r0 = a0; r1 = a1;
}

__device__ __forceinline__ float dot1(const u16* hr, const float* __restrict__ w0p, float b0)
{
  float a0 = b0;
  const float2* W0 = (const float2*)w0p;
#pragma unroll 2
  for (int m = 0; m < 200; ++m) {
    const u32 u = *(const u32*)(hr + 2 * m);
    a0 = fmaf(h2f((u16)(u >> 16)),     W0[m].y,
         fmaf(h2f((u16)(u & 0xffffu)), W0[m].x, a0));
  }
  return a0;
}

__global__ __launch_bounds__(256) void heads_kernel(const float* __restrict__ ws,
                                                    float* __restrict__ out)
{
  __shared__ u16 hs[64 * 402];                 // dword stride 201 -> conflict-free
  const u16*  H3 = (const u16*)(ws + OH3);
  const float* Wh = ws + OWH;
  const float* bh = ws + OBH;
  const int s = blockIdx.x;
  const int tid = threadIdx.x;
  {
    const u32* H3r = (const u32*)(H3 + (size_t)s * 25600);   // [b][400 j] rows
    u32* hs32 = (u32*)hs;
    for (int idx = tid; idx < 64 * 200; idx += 256) {
      const int bb = idx / 200, cc = idx % 200;
      hs32[bb * 201 + cc] = H3r[bb * 200 + cc];
    }
  }
  __syncthreads();
  const int wv = tid >> 6, lane = tid & 63;
  const u16* hr = hs + lane * 402;
  const size_t bs700 = (size_t)lane * 700 + s;

  if (wv == 0) {
    out[OE + bs700] = 1.f / (1.f + expf(dot1(hr, Wh, bh[0])));
    float pl[20];
#pragma unroll
    for (int op = 0; op < 10; ++op) {
      float r0, r1;
      dot2(hr, Wh + (size_t)(1 + 2 * op) * 400, Wh + (size_t)(2 + 2 * op) * 400,
           bh[1 + 2 * op], bh[2 + 2 * op], r0, r1);
      pl[2 * op] = r0; pl[2 * op + 1] = r1;
    }
    float mx = pl[0];
#pragma unroll
    for (int i = 1; i < 20; ++i) mx = fmaxf(mx, pl[i]);
    float sm = 0.f;
#pragma unroll
    for (int i = 0; i < 20; ++i) { pl[i] = expf(pl[i] - mx); sm += pl[i]; }
    const float inv = 1.f / sm;
    float* po = out + OPI + bs700 * 20;
#pragma unroll
    for (int i = 0; i < 20; ++i) po[i] = pl[i] * inv;
  } else if (wv == 1) {
    for (int op = 0; op < 20; ++op) {
      float r0, r1;
      dot2(hr, Wh + (size_t)(21 + 2 * op) * 400, Wh + (size_t)(22 + 2 * op) * 400,
           bh[21 + 2 * op], bh[22 + 2 * op], r0, r1);
      const int o0 = 2 * op, o1 = o0 + 1;
      out[(o0 < 20) ? (OMU1 + bs700 * 20 + o0) : (OMU2 + bs700 * 20 + o0 - 20)] = r0;
      out[(o1 < 20) ? (OMU1 + bs700 * 20 + o1) : (OMU2 + bs700 * 20 + o1 - 20)] = r1;
    }
  } else if (wv == 2) {
    for (int op = 0; op < 20; ++op) {
      float r0, r1;
      dot2(hr, Wh + (size_t)(61 + 2 * op) * 400, Wh + (size_t)(62 + 2 * op) * 400,
           bh[61 + 2 * op], bh[62 + 2 * op], r0, r1);
      const int o0 = 2 * op, o1 = o0 + 1;
      out[(o0 < 20) ? (OSG1 + bs700 * 20 + o0) : (OSG2 + bs700 * 20 + o0 - 20)] = expf(r0);
      out[(o1 < 20) ? (OSG1 + bs700 * 20 + o1) : (OSG2 + bs700 * 20 + o1 - 20)] = expf(r1);
    }
  } else {
    for (int op = 0; op < 10; ++op) {
      float r0, r1;
      dot2(hr, Wh + (size_t)(101 + 2 * op) * 400, Wh + (size_t)(102 + 2 * op) * 400,
           bh[101 + 2 * op], bh[102 + 2 * op], r0, r1);
      float* po = out + ORO + bs700 * 20;
      po[2 * op] = tanhf(r0); po[2 * op + 1] = tanhf(r1);
    }
  }
}

// ---------------- launch ----------------
extern "C" void kernel_launch(void* const* d_in, const int* in_sizes, int n_in,
                              void* d_out, int out_size, void* d_ws, size_t ws_size,
                              hipStream_t stream)
{
  Ptrs in;
  for (int i = 0; i < 33; ++i) in.p[i] = (const float*)d_in[i];
  float* ws  = (float*)d_ws;
  float* out = (float*)d_out;

  hipLaunchKernelGGL(setup_kernel, dim3(4096), dim3(256), 0, stream, in, ws);
  hipLaunchKernelGGL(lstm_scan, dim3(NWG), dim3(512), 0, stream, in, ws, out);
  hipLaunchKernelGGL(heads_kernel, dim3(SS), dim3(256), 0, stream, (const float*)ws, out);
}

// Round 16
// 5904.787 us; speedup vs baseline: 1.5789x; 1.3730x over previous
//
#include <hip/hip_runtime.h>

typedef unsigned short u16;
typedef unsigned int   u32;
typedef unsigned long long u64;
typedef __attribute__((ext_vector_type(8))) _Float16 f16x8;
typedef __attribute__((ext_vector_type(4))) float    f32x4;

constexpr int SS  = 700;
constexpr int NWG = 39;    // 13 WGs per layer; each WG: 32 j x 64 b

// ---- workspace layout (float offsets) ----
constexpr size_t OA1  = 0;        // A-pack L1 [13 jb][8 wv][13 kt][64 lane][8] f16
constexpr size_t OA2  = 346112;   // A-pack L2 [13][8][25][64][8] f16
constexpr size_t OA3  = 1011712;  // A-pack L3
constexpr size_t OWH  = 1677312;  // head weights (3-block-summed) [121][400] f32
constexpr size_t OBH  = 1725712;  // head biases (pad 128)
constexpr size_t OSBT = 1725840;  // u16 [2 parity][64 b][1200 k]  (h1|h2|h3, f16)
constexpr size_t OBAR = 1802640;  // arrival slots @ +wg*16 (39), gen copies @ +768+lf*16 (16)
constexpr size_t OH3  = 1803696;  // u16 [700 t][64 b][400 j]  (f16)

// ---- output layout (float offsets) ----
constexpr size_t OE   = 0;
constexpr size_t OPI  = 44800;
constexpr size_t OMU1 = 940800;
constexpr size_t OMU2 = 1836800;
constexpr size_t OSG1 = 2732800;
constexpr size_t OSG2 = 3628800;
constexpr size_t ORO  = 4524800;
constexpr size_t OST  = 5420800;

struct Ptrs { const float* p[33]; };

union HU { u16 u; _Float16 h; };

__device__ __forceinline__ u16 f2h(float f) {
  HU c; c.h = (_Float16)f; return c.u;
}
__device__ __forceinline__ float h2f(u16 u) {
  HU c; c.u = u; return (float)c.h;
}

// fast sigmoid/tanh: v_exp_f32 + v_rcp_f32, overflow-safe (rcp(inf)=0)
__device__ __forceinline__ float fsigm(float v) {
  return __builtin_amdgcn_rcpf(1.f + __expf(-v));
}
__device__ __forceinline__ float ftanh(float v) {
  return fmaf(2.f, __builtin_amdgcn_rcpf(1.f + __expf(-2.f * v)), -1.f);
}

__device__ __forceinline__ u32 aload(const u32* p) {
  return __hip_atomic_load(p, __ATOMIC_RELAXED, __HIP_MEMORY_SCOPE_AGENT);
}
__device__ __forceinline__ void astore(u32* p, u32 v) {
  __hip_atomic_store(p, v, __ATOMIC_RELAXED, __HIP_MEMORY_SCOPE_AGENT);
}

// ---------------- setup: pack MFMA A-fragments, init states ----------------
__device__ __forceinline__ float apack_val(const Ptrs& in, int layer, size_t i, int KT)
{
  const int e = (int)(i & 7); const int lane = (int)((i >> 3) & 63);
  size_t q = i >> 9; const int kt = (int)(q % KT); q /= KT;
  const int wv = (int)(q & 7); const int jb = (int)(q >> 3);
  const int rw = lane & 15; const int g = rw & 3; const int jq = rw >> 2;
  const int j = jb * 32 + wv * 4 + jq;
  if (j >= 400) return 0.f;
  const int grow = g * 400 + j;
  const int kk = kt * 32 + 8 * (lane >> 4) + e;
  if (layer == 0) return (kk < 400) ? in.p[8][(size_t)grow * 400 + kk] : 0.f;
  const float* Wih = (layer == 1) ? in.p[11] : in.p[15];
  const float* Whh = (layer == 1) ? in.p[12] : in.p[16];
  return (kk < 400) ? Wih[(size_t)grow * 403 + 3 + kk]
                    : Whh[(size_t)grow * 400 + (kk - 400)];
}

__global__ __launch_bounds__(256) void setup_kernel(Ptrs in, float* __restrict__ ws)
{
  u16* wsu = (u16*)ws;
  const size_t TOTAL = 3481001;
  for (size_t idx = (size_t)blockIdx.x * 256 + threadIdx.x; idx < TOTAL;
       idx += (size_t)gridDim.x * 256) {
    size_t i = idx;
    if (i < 692224)  { wsu[OA1 * 2 + i] = f2h(apack_val(in, 0, i, 13)); continue; }
    i -= 692224;
    if (i < 1331200) { wsu[OA2 * 2 + i] = f2h(apack_val(in, 1, i, 25)); continue; }
    i -= 1331200;
    if (i < 1331200) { wsu[OA3 * 2 + i] = f2h(apack_val(in, 2, i, 25)); continue; }
    i -= 1331200;
    if (i < 48400) {                         // head weights: sum 3 400-blocks
      const int o = (int)(i / 400), k = (int)(i % 400);
      int src, row;
      if      (o == 0)  { src = 19; row = 0; }
      else if (o < 21)  { src = 21; row = o - 1; }
      else if (o < 41)  { src = 23; row = o - 21; }
      else if (o < 61)  { src = 25; row = o - 41; }
      else if (o < 81)  { src = 27; row = o - 61; }
      else if (o < 101) { src = 29; row = o - 81; }
      else              { src = 31; row = o - 101; }
      const float* W = in.p[src] + (size_t)row * 1200;
      ws[OWH + i] = W[k] + W[400 + k] + W[800 + k];
      continue;
    }
    i -= 48400;
    if (i < 121) {                           // head biases
      const int o = (int)i;
      int src, row;
      if      (o == 0)  { src = 20; row = 0; }
      else if (o < 21)  { src = 22; row = o - 1; }
      else if (o < 41)  { src = 24; row = o - 21; }
      else if (o < 61)  { src = 26; row = o - 41; }
      else if (o < 81)  { src = 28; row = o - 61; }
      else if (o < 101) { src = 30; row = o - 81; }
      else              { src = 32; row = o - 101; }
      ws[OBH + i] = in.p[src][row];
      continue;
    }
    i -= 121;
    if (i < 76800) {                         // initial h states -> SBT (f16)
      const int cell = (int)(i / 25600);
      const int rr = (int)(i % 25600);
      const int j = rr >> 6, b = rr & 63;
      const int par = (cell == 1) ? 0 : 1;   // h1->p1, h2->p0, h3->p1
      wsu[OSBT * 2 + (size_t)par * 76800 + (size_t)b * 1200 + cell * 400 + j] =
          f2h(in.p[1 + cell * 2][(size_t)b * 400 + j]);
      continue;
    }
    i -= 76800;
    if (i < 1056) ((u32*)(ws + OBAR))[i] = 0u;
  }
}

// ------------- grid barrier: zero-RMW master-poll, monotone counters -------------
// Arrival: each WG STORES tick n+1 to its own slot (no RMW -> no same-line convoys).
// WG 0's wave 0 gather-polls the 39 slots (one lane each; dup lanes share line 0 via
// same-address broadcast; s_sleep backoff), then 16 lanes store the 16 replicated
// gen copies IN PARALLEL (1 RT vs 16 serial). Other WGs poll their own gen copy
// (<=3 pollers/line). Monotone values, no resets, no HW fences (data path is
// MALL-bypass atomics; __syncthreads drains vmcnt before the arrival store).
__device__ __forceinline__ void grid_barrier(u32* bar, int n)
{
  __syncthreads();                       // drains publish stores of all waves
  if (threadIdx.x == 0)
    astore(bar + (size_t)blockIdx.x * 16, (u32)(n + 1));
  if (blockIdx.x == 0) {
    if (threadIdx.x < 64) {
      const int idx = ((int)threadIdx.x < NWG) ? (int)threadIdx.x : 0;
      const u32* cp = bar + (size_t)idx * 16;
      while (__ballot(aload(cp) >= (u32)(n + 1)) != ~0ull)
        __builtin_amdgcn_s_sleep(1);
      if (threadIdx.x < 16)
        astore(bar + 768 + (size_t)threadIdx.x * 16, (u32)(n + 1));
    }
  } else if (threadIdx.x == 0) {
    const u32* gen = bar + 768 + (size_t)(blockIdx.x & 15) * 16;
    while (aload(gen) < (u32)(n + 1))
      __builtin_amdgcn_s_sleep(1);
    __atomic_signal_fence(__ATOMIC_SEQ_CST);
  }
  __syncthreads();
}

// ---------------- scan body ----------------
template<int LAYER>
__device__ __forceinline__ void scan_body(Ptrs in, float* __restrict__ ws,
                                          float* __restrict__ out, char* __restrict__ lds,
                                          u16 (*hstage)[32])
{
  constexpr int KT   = (LAYER == 0) ? 13 : 25;     // K tiles of 32 (L1 padded 400->416)
  constexpr int RB   = KT * 64 + 16;               // LDS row bytes (+8 f16 pad)
  constexpr int CH   = KT * 8;                     // u64 chunks per row (104 / 200)
  constexpr int TOT  = 64 * CH;                    // total u64 chunks (6656 / 12800)
  constexpr int COL0 = (LAYER == 2) ? 400 : 0;     // SBT col origin (f16 idx)
  constexpr int WCOL = LAYER * 400;                // write col base
  constexpr size_t OA = (LAYER == 0) ? OA1 : ((LAYER == 1) ? OA2 : OA3);

  const int jb   = (int)blockIdx.x - 13 * LAYER;
  const int tid  = (int)threadIdx.x;
  const int lane = tid & 63;
  const int wv   = tid >> 6;          // 0..7 : j-quad owner
  const int jq   = lane >> 4;         // 0..3
  const int bcol = lane & 15;

  u16* SBT = (u16*)(ws + OSBT);
  u16* H3  = (u16*)(ws + OH3);
  u32* bar = (u32*)(ws + OBAR);
  const float* x = in.p[0];

  const int j = jb * 32 + wv * 4 + jq;
  const bool jok = (j < 400);

  // finalize constants (per-lane)
  float xw[12], bias[4], cr[4];
  {
    const float* Wx = (LAYER == 0) ? in.p[7]  : ((LAYER == 1) ? in.p[11] : in.p[15]);
    const int    xs = (LAYER == 0) ? 3 : 403;
    const float* b0 = (LAYER == 0) ? in.p[9]  : ((LAYER == 1) ? in.p[13] : in.p[17]);
    const float* b1 = (LAYER == 0) ? in.p[10] : ((LAYER == 1) ? in.p[14] : in.p[18]);
    const float* ci = (LAYER == 0) ? in.p[2]  : ((LAYER == 1) ? in.p[4]  : in.p[6]);
#pragma unroll
    for (int g = 0; g < 4; ++g) {
      const int grow = g * 400 + j;
#pragma unroll
      for (int dk = 0; dk < 3; ++dk)
        xw[g * 3 + dk] = jok ? Wx[(size_t)grow * xs + dk] : 0.f;
      bias[g] = jok ? (b0[grow] + b1[grow]) : 0.f;
    }
#pragma unroll
    for (int bt = 0; bt < 4; ++bt)
      cr[bt] = jok ? ci[(size_t)(bt * 16 + bcol) * 400 + j] : 0.f;
  }

  // A-fragments (weights) -> registers, resident for the whole scan
  f16x8 A[KT];
  {
    const u16* ap = (u16*)ws + OA * 2 + ((size_t)(jb * 8 + wv) * KT * 64 + lane) * 8;
#pragma unroll
    for (int kt = 0; kt < KT; ++kt)
      A[kt] = *(const f16x8*)(ap + (size_t)kt * 512);
  }

  for (int n = 0; n < 702; ++n) {
    const int p = n & 1;
    const int t = n - LAYER;
    const bool active = (t >= 0) && (t < SS);
    float xv[12];
    if (active) {
#pragma unroll
      for (int bt = 0; bt < 4; ++bt) {
        const float* xp = x + (size_t)t * 192 + (bt * 16 + bcol) * 3;
        xv[bt * 3] = xp[0]; xv[bt * 3 + 1] = xp[1]; xv[bt * 3 + 2] = xp[2];
      }
      // stage h: MALL-bypass u64 atomic loads (4 f16 each) -> LDS, 5 in flight
      // (measured optimum: depth-5 rounds beat depth-13/25 bursts, R13 vs R15/R10)
      const u64* src = (const u64*)(SBT + (size_t)(p ^ 1) * 76800 + COL0);  // row = 300 u64
      for (int base = tid; base < TOT; base += 512 * 5) {
        u64 tv[5];
#pragma unroll
        for (int i = 0; i < 5; ++i) {
          const int c = base + i * 512;
          if (c < TOT)
            tv[i] = __hip_atomic_load(src + (size_t)(c / CH) * 300 + (c % CH),
                                      __ATOMIC_RELAXED, __HIP_MEMORY_SCOPE_AGENT);
        }
#pragma unroll
        for (int i = 0; i < 5; ++i) {
          const int c = base + i * 512;
          if (c < TOT)
            *(u64*)(lds + (size_t)(c / CH) * RB + (size_t)(c % CH) * 8) = tv[i];
        }
      }
    }
    __syncthreads();
    if (active) {
      f32x4 acc[4];
#pragma unroll
      for (int bt = 0; bt < 4; ++bt) acc[bt] = (f32x4){0.f, 0.f, 0.f, 0.f};
#pragma unroll
      for (int kt = 0; kt < KT; ++kt) {
#pragma unroll
        for (int bt = 0; bt < 4; ++bt) {
          const f16x8 bv = *(const f16x8*)(lds + (size_t)(bt * 16 + bcol) * RB
                                               + jq * 16 + kt * 64);
          acc[bt] = __builtin_amdgcn_mfma_f32_16x16x32_f16(A[kt], bv, acc[bt], 0, 0, 0);
        }
      }
      if (jok) {
#pragma unroll
        for (int bt = 0; bt < 4; ++bt) {
          const int b = bt * 16 + bcol;
          float gv[4];
#pragma unroll
          for (int g = 0; g < 4; ++g)
            gv[g] = acc[bt][g] + bias[g] + xv[bt * 3] * xw[g * 3]
                  + xv[bt * 3 + 1] * xw[g * 3 + 1] + xv[bt * 3 + 2] * xw[g * 3 + 2];
          const float fi = fsigm(gv[0]), ff = fsigm(gv[1]);
          const float gg = ftanh(gv[2]), oo = fsigm(gv[3]);
          const float cn = ff * cr[bt] + fi * gg;
          const float hn = oo * ftanh(cn);
          cr[bt] = cn;
          hstage[b][wv * 4 + jq] = f2h(hn);             // pack via LDS (contiguous publish)
          if (LAYER == 2) H3[((size_t)t * 64 + b) * 400 + j] = f2h(hn);
          if (t == SS - 1) {
            out[OST + (size_t)(LAYER * 2) * 25600     + (size_t)b * 400 + j] = hn;
            out[OST + (size_t)(LAYER * 2 + 1) * 25600 + (size_t)b * 400 + j] = cn;
          }
        }
      }
    }
    __syncthreads();
    if (active) {
      // publish h-slice: 2 MALL-bypass u32 atomic stores per thread (2 f16 each),
      // consecutive threads -> consecutive dwords (contiguous 64B runs per b-row)
      const u32* hs32 = (const u32*)hstage;
      for (int c = tid; c < 1024; c += 512) {
        const int b = c >> 4, jp = c & 15;
        if (jb * 32 + jp * 2 < 400)
          __hip_atomic_store((u32*)SBT + (size_t)p * 38400 + (size_t)b * 600
                                 + (WCOL + jb * 32) / 2 + jp,
                             hs32[c], __ATOMIC_RELAXED, __HIP_MEMORY_SCOPE_AGENT);
      }
    }
    if (n < 701) grid_barrier(bar, n);
  }
}

// Normal launch: 39 WGs on 256 CUs are always co-resident (1 WG/CU, LDS-limited).
__global__ __launch_bounds__(512, 2) void lstm_scan(Ptrs in, float* __restrict__ ws,
                                                    float* __restrict__ out)
{
  __shared__ __align__(16) char lds[103424];   // 64 rows x 1616 B (L1 uses 54272)
  __shared__ u16 hstage[64][32];               // h repack for paired u32 stores
  if (blockIdx.x < 13)      scan_body<0>(in, ws, out, lds, hstage);
  else if (blockIdx.x < 26) scan_body<1>(in, ws, out, lds, hstage);
  else                      scan_body<2>(in, ws, out, lds, hstage);
}

// ---------------- MDN heads ----------------
__device__ __forceinline__ void dot2(const u16* hr,
    const float* __restrict__ w0p, const float* __restrict__ w1p,
    float b0, float b1, float& r0, float& r1)
{
  float a0 = b0, a1 = b1;
  const float2* W0 = (const float2*)w0p;
  const float2* W1 = (const float2*)w1p;
#pragma unroll 2
  for (int m = 0; m < 200; ++m) {
    const u32 u = *(const u32*)(hr + 2 * m);
    const float lo = h2f((u16)(u & 0xffffu));
    const float hi = h2f((u16)(u >> 16));
    const float2 c0 = W0[m], c1 = W1[m];
    a0 = fmaf(hi, c0.y, fmaf(lo, c0.x, a0));
    a1 = fmaf(hi, c1.y, fmaf(lo, c1.x, a1));
  }
  r0 = a0; r1 = a1;
}

__device__ __forceinline__ float dot1(const u16* hr, const float* __restrict__ w0p, float b0)
{
  float a0 = b0;
  const float2* W0 = (const float2*)w0p;
#pragma unroll 2
  for (int m = 0; m < 200; ++m) {
    const u32 u = *(const u32*)(hr + 2 * m);
    a0 = fmaf(h2f((u16)(u >> 16)),     W0[m].y,
         fmaf(h2f((u16)(u & 0xffffu)), W0[m].x, a0));
  }
  return a0;
}

__global__ __launch_bounds__(256) void heads_kernel(const float* __restrict__ ws,
                                                    float* __restrict__ out)
{
  __shared__ u16 hs[64 * 402];                 // dword stride 201 -> conflict-free
  const u16*  H3 = (const u16*)(ws + OH3);
  const float* Wh = ws + OWH;
  const float* bh = ws + OBH;
  const int s = blockIdx.x;
  const int tid = threadIdx.x;
  {
    const u32* H3r = (const u32*)(H3 + (size_t)s * 25600);   // [b][400 j] rows
    u32* hs32 = (u32*)hs;
    for (int idx = tid; idx < 64 * 200; idx += 256) {
      const int bb = idx / 200, cc = idx % 200;
      hs32[bb * 201 + cc] = H3r[bb * 200 + cc];
    }
  }
  __syncthreads();
  const int wv = tid >> 6, lane = tid & 63;
  const u16* hr = hs + lane * 402;
  const size_t bs700 = (size_t)lane * 700 + s;

  if (wv == 0) {
    out[OE + bs700] = 1.f / (1.f + expf(dot1(hr, Wh, bh[0])));
    float pl[20];
#pragma unroll
    for (int op = 0; op < 10; ++op) {
      float r0, r1;
      dot2(hr, Wh + (size_t)(1 + 2 * op) * 400, Wh + (size_t)(2 + 2 * op) * 400,
           bh[1 + 2 * op], bh[2 + 2 * op], r0, r1);
      pl[2 * op] = r0; pl[2 * op + 1] = r1;
    }
    float mx = pl[0];
#pragma unroll
    for (int i = 1; i < 20; ++i) mx = fmaxf(mx, pl[i]);
    float sm = 0.f;
#pragma unroll
    for (int i = 0; i < 20; ++i) { pl[i] = expf(pl[i] - mx); sm += pl[i]; }
    const float inv = 1.f / sm;
    float* po = out + OPI + bs700 * 20;
#pragma unroll
    for (int i = 0; i < 20; ++i) po[i] = pl[i] * inv;
  } else if (wv == 1) {
    for (int op = 0; op < 20; ++op) {
      float r0, r1;
      dot2(hr, Wh + (size_t)(21 + 2 * op) * 400, Wh + (size_t)(22 + 2 * op) * 400,
           bh[21 + 2 * op], bh[22 + 2 * op], r0, r1);
      const int o0 = 2 * op, o1 = o0 + 1;
      out[(o0 < 20) ? (OMU1 + bs700 * 20 + o0) : (OMU2 + bs700 * 20 + o0 - 20)] = r0;
      out[(o1 < 20) ? (OMU1 + bs700 * 20 + o1) : (OMU2 + bs700 * 20 + o1 - 20)] = r1;
    }
  } else if (wv == 2) {
    for (int op = 0; op < 20; ++op) {
      float r0, r1;
      dot2(hr, Wh + (size_t)(61 + 2 * op) * 400, Wh + (size_t)(62 + 2 * op) * 400,
           bh[61 + 2 * op], bh[62 + 2 * op], r0, r1);
      const int o0 = 2 * op, o1 = o0 + 1;
      out[(o0 < 20) ? (OSG1 + bs700 * 20 + o0) : (OSG2 + bs700 * 20 + o0 - 20)] = expf(r0);
      out[(o1 < 20) ? (OSG1 + bs700 * 20 + o1) : (OSG2 + bs700 * 20 + o1 - 20)] = expf(r1);
    }
  } else {
    for (int op = 0; op < 10; ++op) {
      float r0, r1;
      dot2(hr, Wh + (size_t)(101 + 2 * op) * 400, Wh + (size_t)(102 + 2 * op) * 400,
           bh[101 + 2 * op], bh[102 + 2 * op], r0, r1);
      float* po = out + ORO + bs700 * 20;
      po[2 * op] = tanhf(r0); po[2 * op + 1] = tanhf(r1);
    }
  }
}

// ---------------- launch ----------------
extern "C" void kernel_launch(void* const* d_in, const int* in_sizes, int n_in,
                              void* d_out, int out_size, void* d_ws, size_t ws_size,
                              hipStream_t stream)
{
  Ptrs in;
  for (int i = 0; i < 33; ++i) in.p[i] = (const float*)d_in[i];
  float* ws  = (float*)d_ws;
  float* out = (float*)d_out;

  hipLaunchKernelGGL(setup_kernel, dim3(4096), dim3(256), 0, stream, in, ws);
  hipLaunchKernelGGL(lstm_scan, dim3(NWG), dim3(512), 0, stream, in, ws, out);
  hipLaunchKernelGGL(heads_kernel, dim3(SS), dim3(256), 0, stream, (const float*)ws, out);
}

// Round 17
// 5143.964 us; speedup vs baseline: 1.8124x; 1.1479x over previous
//
#include <hip/hip_runtime.h>

typedef unsigned short u16;
typedef unsigned int   u32;
typedef unsigned long long u64;
typedef __attribute__((ext_vector_type(8))) _Float16 f16x8;
typedef __attribute__((ext_vector_type(4))) float    f32x4;

constexpr int SS  = 700;
constexpr int NWG = 39;    // 13 WGs per layer; each WG: 32 j x 64 b

// ---- workspace layout (float offsets) ----
constexpr size_t OA1  = 0;        // A-pack L1 [13 jb][8 wv][13 kt][64 lane][8] f16
constexpr size_t OA2  = 346112;   // A-pack L2 [13][8][25][64][8] f16
constexpr size_t OA3  = 1011712;  // A-pack L3
constexpr size_t OWH  = 1677312;  // head weights (3-block-summed) [121][400] f32
constexpr size_t OBH  = 1725712;  // head biases (pad 128)
constexpr size_t OSBT = 1725840;  // u16 [2 parity][64 b][1200 k]  (h1|h2|h3, f16)
constexpr size_t OBAR = 1802640;  // arrival slots @ +wg*16 (39), gen copies @ +768+lf*16 (16)
constexpr size_t OH3  = 1803696;  // u16 [700 t][64 b][400 j]  (f16)

// ---- output layout (float offsets) ----
constexpr size_t OE   = 0;
constexpr size_t OPI  = 44800;
constexpr size_t OMU1 = 940800;
constexpr size_t OMU2 = 1836800;
constexpr size_t OSG1 = 2732800;
constexpr size_t OSG2 = 3628800;
constexpr size_t ORO  = 4524800;
constexpr size_t OST  = 5420800;

struct Ptrs { const float* p[33]; };

union HU { u16 u; _Float16 h; };

__device__ __forceinline__ u16 f2h(float f) {
  HU c; c.h = (_Float16)f; return c.u;
}
__device__ __forceinline__ float h2f(u16 u) {
  HU c; c.u = u; return (float)c.h;
}

// fast sigmoid/tanh: v_exp_f32 + v_rcp_f32, overflow-safe (rcp(inf)=0)
__device__ __forceinline__ float fsigm(float v) {
  return __builtin_amdgcn_rcpf(1.f + __expf(-v));
}
__device__ __forceinline__ float ftanh(float v) {
  return fmaf(2.f, __builtin_amdgcn_rcpf(1.f + __expf(-2.f * v)), -1.f);
}

__device__ __forceinline__ u32 aload(const u32* p) {
  return __hip_atomic_load(p, __ATOMIC_RELAXED, __HIP_MEMORY_SCOPE_AGENT);
}
__device__ __forceinline__ void astore(u32* p, u32 v) {
  __hip_atomic_store(p, v, __ATOMIC_RELAXED, __HIP_MEMORY_SCOPE_AGENT);
}
__device__ __forceinline__ u64 aload64(const u64* p) {
  return __hip_atomic_load(p, __ATOMIC_RELAXED, __HIP_MEMORY_SCOPE_AGENT);
}

// ---------------- setup: pack MFMA A-fragments, init states ----------------
__device__ __forceinline__ float apack_val(const Ptrs& in, int layer, size_t i, int KT)
{
  const int e = (int)(i & 7); const int lane = (int)((i >> 3) & 63);
  size_t q = i >> 9; const int kt = (int)(q % KT); q /= KT;
  const int wv = (int)(q & 7); const int jb = (int)(q >> 3);
  const int rw = lane & 15; const int g = rw & 3; const int jq = rw >> 2;
  const int j = jb * 32 + wv * 4 + jq;
  if (j >= 400) return 0.f;
  const int grow = g * 400 + j;
  const int kk = kt * 32 + 8 * (lane >> 4) + e;
  if (layer == 0) return (kk < 400) ? in.p[8][(size_t)grow * 400 + kk] : 0.f;
  const float* Wih = (layer == 1) ? in.p[11] : in.p[15];
  const float* Whh = (layer == 1) ? in.p[12] : in.p[16];
  return (kk < 400) ? Wih[(size_t)grow * 403 + 3 + kk]
                    : Whh[(size_t)grow * 400 + (kk - 400)];
}

__global__ __launch_bounds__(256) void setup_kernel(Ptrs in, float* __restrict__ ws)
{
  u16* wsu = (u16*)ws;
  const size_t TOTAL = 3481001;
  for (size_t idx = (size_t)blockIdx.x * 256 + threadIdx.x; idx < TOTAL;
       idx += (size_t)gridDim.x * 256) {
    size_t i = idx;
    if (i < 692224)  { wsu[OA1 * 2 + i] = f2h(apack_val(in, 0, i, 13)); continue; }
    i -= 692224;
    if (i < 1331200) { wsu[OA2 * 2 + i] = f2h(apack_val(in, 1, i, 25)); continue; }
    i -= 1331200;
    if (i < 1331200) { wsu[OA3 * 2 + i] = f2h(apack_val(in, 2, i, 25)); continue; }
    i -= 1331200;
    if (i < 48400) {                         // head weights: sum 3 400-blocks
      const int o = (int)(i / 400), k = (int)(i % 400);
      int src, row;
      if      (o == 0)  { src = 19; row = 0; }
      else if (o < 21)  { src = 21; row = o - 1; }
      else if (o < 41)  { src = 23; row = o - 21; }
      else if (o < 61)  { src = 25; row = o - 41; }
      else if (o < 81)  { src = 27; row = o - 61; }
      else if (o < 101) { src = 29; row = o - 81; }
      else              { src = 31; row = o - 101; }
      const float* W = in.p[src] + (size_t)row * 1200;
      ws[OWH + i] = W[k] + W[400 + k] + W[800 + k];
      continue;
    }
    i -= 48400;
    if (i < 121) {                           // head biases
      const int o = (int)i;
      int src, row;
      if      (o == 0)  { src = 20; row = 0; }
      else if (o < 21)  { src = 22; row = o - 1; }
      else if (o < 41)  { src = 24; row = o - 21; }
      else if (o < 61)  { src = 26; row = o - 41; }
      else if (o < 81)  { src = 28; row = o - 61; }
      else if (o < 101) { src = 30; row = o - 81; }
      else              { src = 32; row = o - 101; }
      ws[OBH + i] = in.p[src][row];
      continue;
    }
    i -= 121;
    if (i < 76800) {                         // initial h states -> SBT (f16)
      const int cell = (int)(i / 25600);
      const int rr = (int)(i % 25600);
      const int j = rr >> 6, b = rr & 63;
      const int par = (cell == 1) ? 0 : 1;   // h1->p1, h2->p0, h3->p1
      wsu[OSBT * 2 + (size_t)par * 76800 + (size_t)b * 1200 + cell * 400 + j] =
          f2h(in.p[1 + cell * 2][(size_t)b * 400 + j]);
      continue;
    }
    i -= 76800;
    if (i < 1056) ((u32*)(ws + OBAR))[i] = 0u;
  }
}

// ------------- grid barrier: zero-RMW master-poll, monotone counters -------------
// Arrival: each WG STORES tick n+1 to its own slot (no RMW -> no same-line convoys).
// WG 0's wave 0 gather-polls the 39 slots (one lane each; s_sleep backoff), then 16
// lanes store the 16 replicated gen copies IN PARALLEL. Other WGs poll their own gen
// copy (<=3 pollers/line). Monotone values, no resets, no HW fences (data path is
// MALL-bypass atomics; __syncthreads drains vmcnt before the arrival store).
// Measured (R16): removes the multi-ms outlier replays entirely; variance < 0.2%.
__device__ __forceinline__ void grid_barrier(u32* bar, int n)
{
  __syncthreads();                       // drains publish stores of all waves
  if (threadIdx.x == 0)
    astore(bar + (size_t)blockIdx.x * 16, (u32)(n + 1));
  if (blockIdx.x == 0) {
    if (threadIdx.x < 64) {
      const int idx = ((int)threadIdx.x < NWG) ? (int)threadIdx.x : 0;
      const u32* cp = bar + (size_t)idx * 16;
      while (__ballot(aload(cp) >= (u32)(n + 1)) != ~0ull)
        __builtin_amdgcn_s_sleep(1);
      if (threadIdx.x < 16)
        astore(bar + 768 + (size_t)threadIdx.x * 16, (u32)(n + 1));
    }
  } else if (threadIdx.x == 0) {
    const u32* gen = bar + 768 + (size_t)(blockIdx.x & 15) * 16;
    while (aload(gen) < (u32)(n + 1))
      __builtin_amdgcn_s_sleep(1);
    __atomic_signal_fence(__ATOMIC_SEQ_CST);
  }
  __syncthreads();
}

// ---------------- scan body ----------------
template<int LAYER>
__device__ __forceinline__ void scan_body(Ptrs in, float* __restrict__ ws,
                                          float* __restrict__ out, char* __restrict__ lds,
                                          u16 (*hstage)[32])
{
  constexpr int KT   = (LAYER == 0) ? 13 : 25;     // K tiles of 32 (L1 padded 400->416)
  constexpr int RB   = KT * 64 + 16;               // LDS row bytes (+8 f16 pad)
  constexpr int CH   = KT * 8;                     // u64 chunks per row (104 / 200)
  constexpr int COL0 = (LAYER == 2) ? 400 : 0;     // SBT col origin (f16 idx)
  constexpr int WCOL = LAYER * 400;                // write col base
  constexpr size_t OA = (LAYER == 0) ? OA1 : ((LAYER == 1) ? OA2 : OA3);

  const int jb   = (int)blockIdx.x - 13 * LAYER;
  const int tid  = (int)threadIdx.x;
  const int lane = tid & 63;
  const int wv   = tid >> 6;          // 0..7 : j-quad owner
  const int jq   = lane >> 4;         // 0..3
  const int bcol = lane & 15;

  u16* SBT = (u16*)(ws + OSBT);
  u16* H3  = (u16*)(ws + OH3);
  u32* bar = (u32*)(ws + OBAR);
  const float* x = in.p[0];

  const int j = jb * 32 + wv * 4 + jq;
  const bool jok = (j < 400);

  // finalize constants (per-lane)
  float xw[12], bias[4], cr[4];
  {
    const float* Wx = (LAYER == 0) ? in.p[7]  : ((LAYER == 1) ? in.p[11] : in.p[15]);
    const int    xs = (LAYER == 0) ? 3 : 403;
    const float* b0 = (LAYER == 0) ? in.p[9]  : ((LAYER == 1) ? in.p[13] : in.p[17]);
    const float* b1 = (LAYER == 0) ? in.p[10] : ((LAYER == 1) ? in.p[14] : in.p[18]);
    const float* ci = (LAYER == 0) ? in.p[2]  : ((LAYER == 1) ? in.p[4]  : in.p[6]);
#pragma unroll
    for (int g = 0; g < 4; ++g) {
      const int grow = g * 400 + j;
#pragma unroll
      for (int dk = 0; dk < 3; ++dk)
        xw[g * 3 + dk] = jok ? Wx[(size_t)grow * xs + dk] : 0.f;
      bias[g] = jok ? (b0[grow] + b1[grow]) : 0.f;
    }
#pragma unroll
    for (int bt = 0; bt < 4; ++bt)
      cr[bt] = jok ? ci[(size_t)(bt * 16 + bcol) * 400 + j] : 0.f;
  }

  // A-fragments (weights) -> registers, resident for the whole scan
  f16x8 A[KT];
  {
    const u16* ap = (u16*)ws + OA * 2 + ((size_t)(jb * 8 + wv) * KT * 64 + lane) * 8;
#pragma unroll
    for (int kt = 0; kt < KT; ++kt)
      A[kt] = *(const f16x8*)(ap + (size_t)kt * 512);
  }

  // hoisted staging offsets (loop-invariant; statically indexed -> registers)
  u32 soff[KT], loff[KT];
#pragma unroll
  for (int i = 0; i < KT; ++i) {
    const int c = tid + i * 512;
    soff[i] = (u32)((c / CH) * 300 + (c % CH));          // u64 units in SBT row space
    loff[i] = (u32)((c / CH) * RB + (c % CH) * 8);       // bytes in LDS
  }

  for (int n = 0; n < 702; ++n) {
    const int p = n & 1;
    const int t = n - LAYER;
    const bool active = (t >= 0) && (t < SS);
    float xv[12];
    if (active) {
#pragma unroll
      for (int bt = 0; bt < 4; ++bt) {
        const float* xp = x + (size_t)t * 192 + (bt * 16 + bcol) * 3;
        xv[bt * 3] = xp[0]; xv[bt * 3 + 1] = xp[1]; xv[bt * 3 + 2] = xp[2];
      }
      // stage h: MALL-bypass u64 atomic loads -> LDS, software-pipelined rounds of 5
      // (<=10 outstanding: below measured congestion knee; next round's loads issue
      //  before current round's drain -> ~1 MALL RT total instead of 5)
      const u64* src = (const u64*)(SBT + (size_t)(p ^ 1) * 76800 + COL0);
      u64 ta[5], tb[5];
      if constexpr (KT == 25) {
#pragma unroll
        for (int i = 0; i < 5; ++i) ta[i] = aload64(src + soff[i]);
#pragma unroll
        for (int i = 0; i < 5; ++i) tb[i] = aload64(src + soff[5 + i]);
#pragma unroll
        for (int i = 0; i < 5; ++i) *(u64*)(lds + loff[i]) = ta[i];
#pragma unroll
        for (int i = 0; i < 5; ++i) ta[i] = aload64(src + soff[10 + i]);
#pragma unroll
        for (int i = 0; i < 5; ++i) *(u64*)(lds + loff[5 + i]) = tb[i];
#pragma unroll
        for (int i = 0; i < 5; ++i) tb[i] = aload64(src + soff[15 + i]);
#pragma unroll
        for (int i = 0; i < 5; ++i) *(u64*)(lds + loff[10 + i]) = ta[i];
#pragma unroll
        for (int i = 0; i < 5; ++i) ta[i] = aload64(src + soff[20 + i]);
#pragma unroll
        for (int i = 0; i < 5; ++i) *(u64*)(lds + loff[15 + i]) = tb[i];
#pragma unroll
        for (int i = 0; i < 5; ++i) *(u64*)(lds + loff[20 + i]) = ta[i];
      } else {   // KT == 13: rounds 5 + 5 + 3
#pragma unroll
        for (int i = 0; i < 5; ++i) ta[i] = aload64(src + soff[i]);
#pragma unroll
        for (int i = 0; i < 5; ++i) tb[i] = aload64(src + soff[5 + i]);
#pragma unroll
        for (int i = 0; i < 5; ++i) *(u64*)(lds + loff[i]) = ta[i];
#pragma unroll
        for (int i = 0; i < 3; ++i) ta[i] = aload64(src + soff[10 + i]);
#pragma unroll
        for (int i = 0; i < 5; ++i) *(u64*)(lds + loff[5 + i]) = tb[i];
#pragma unroll
        for (int i = 0; i < 3; ++i) *(u64*)(lds + loff[10 + i]) = ta[i];
      }
    }
    __syncthreads();
    if (active) {
      f32x4 acc[4];
#pragma unroll
      for (int bt = 0; bt < 4; ++bt) acc[bt] = (f32x4){0.f, 0.f, 0.f, 0.f};
#pragma unroll
      for (int kt = 0; kt < KT; ++kt) {
#pragma unroll
        for (int bt = 0; bt < 4; ++bt) {
          const f16x8 bv = *(const f16x8*)(lds + (size_t)(bt * 16 + bcol) * RB
                                               + jq * 16 + kt * 64);
          acc[bt] = __builtin_amdgcn_mfma_f32_16x16x32_f16(A[kt], bv, acc[bt], 0, 0, 0);
        }
      }
      if (jok) {
#pragma unroll
        for (int bt = 0; bt < 4; ++bt) {
          const int b = bt * 16 + bcol;
          float gv[4];
#pragma unroll
          for (int g = 0; g < 4; ++g)
            gv[g] = acc[bt][g] + bias[g] + xv[bt * 3] * xw[g * 3]
                  + xv[bt * 3 + 1] * xw[g * 3 + 1] + xv[bt * 3 + 2] * xw[g * 3 + 2];
          const float fi = fsigm(gv[0]), ff = fsigm(gv[1]);
          const float gg = ftanh(gv[2]), oo = fsigm(gv[3]);
          const float cn = ff * cr[bt] + fi * gg;
          const float hn = oo * ftanh(cn);
          cr[bt] = cn;
          hstage[b][wv * 4 + jq] = f2h(hn);             // pack via LDS (contiguous publish)
          if (LAYER == 2) H3[((size_t)t * 64 + b) * 400 + j] = f2h(hn);
          if (t == SS - 1) {
            out[OST + (size_t)(LAYER * 2) * 25600     + (size_t)b * 400 + j] = hn;
            out[OST + (size_t)(LAYER * 2 + 1) * 25600 + (size_t)b * 400 + j] = cn;
          }
        }
      }
    }
    __syncthreads();
    if (active) {
      // publish h-slice: 2 MALL-bypass u32 atomic stores per thread (2 f16 each),
      // consecutive threads -> consecutive dwords (contiguous 64B runs per b-row)
      const u32* hs32 = (const u32*)hstage;
      for (int c = tid; c < 1024; c += 512) {
        const int b = c >> 4, jp = c & 15;
        if (jb * 32 + jp * 2 < 400)
          __hip_atomic_store((u32*)SBT + (size_t)p * 38400 + (size_t)b * 600
                                 + (WCOL + jb * 32) / 2 + jp,
                             hs32[c], __ATOMIC_RELAXED, __HIP_MEMORY_SCOPE_AGENT);
      }
    }
    if (n < 701) grid_barrier(bar, n);
  }
}

// Normal launch: 39 WGs on 256 CUs are always co-resident (1 WG/CU, LDS-limited).
__global__ __launch_bounds__(512, 2) void lstm_scan(Ptrs in, float* __restrict__ ws,
                                                    float* __restrict__ out)
{
  __shared__ __align__(16) char lds[103424];   // 64 rows x 1616 B (L1 uses 54272)
  __shared__ u16 hstage[64][32];               // h repack for paired u32 stores
  if (blockIdx.x < 13)      scan_body<0>(in, ws, out, lds, hstage);
  else if (blockIdx.x < 26) scan_body<1>(in, ws, out, lds, hstage);
  else                      scan_body<2>(in, ws, out, lds, hstage);
}

// ---------------- MDN heads ----------------
__device__ __forceinline__ void dot2(const u16* hr,
    const float* __restrict__ w0p, const float* __restrict__ w1p,
    float b0, float b1, float& r0, float& r1)
{
  float a0 = b0, a1 = b1;
  const float2* W0 = (const float2*)w0p;
  const float2* W1 = (const float2*)w1p;
#pragma unroll 2
  for (int m = 0; m < 200; ++m) {
    const u32 u = *(const u32*)(hr + 2 * m);
    const float lo = h2f((u16)(u & 0xffffu));
    const float hi = h2f((u16)(u >> 16));
    const float2 c0 = W0[m], c1 = W1[m];
    a0 = fmaf(hi, c0.y, fmaf(lo, c0.x, a0));
    a1 = fmaf(hi, c1.y, fmaf(lo, c1.x, a1));
  }
  r0 = a0; r1 = a1;
}

__device__ __forceinline__ float dot1(const u16* hr, const float* __restrict__ w0p, float b0)
{
  float a0 = b0;
  const float2* W0 = (const float2*)w0p;
#pragma unroll 2
  for (int m = 0; m < 200; ++m) {
    const u32 u = *(const u32*)(hr + 2 * m);
    a0 = fmaf(h2f((u16)(u >> 16)),     W0[m].y,
         fmaf(h2f((u16)(u & 0xffffu)), W0[m].x, a0));
  }
  return a0;
}

__global__ __launch_bounds__(256) void heads_kernel(const float* __restrict__ ws,
                                                    float* __restrict__ out)
{
  __shared__ u16 hs[64 * 402];                 // dword stride 201 -> conflict-free
  const u16*  H3 = (const u16*)(ws + OH3);
  const float* Wh = ws + OWH;
  const float* bh = ws + OBH;
  const int s = blockIdx.x;
  const int tid = threadIdx.x;
  {
    const u32* H3r = (const u32*)(H3 + (size_t)s * 25600);   // [b][400 j] rows
    u32* hs32 = (u32*)hs;
    for (int idx = tid; idx < 64 * 200; idx += 256) {
      const int bb = idx / 200, cc = idx % 200;
      hs32[bb * 201 + cc] = H3r[bb * 200 + cc];
    }
  }
  __syncthreads();
  const int wv = tid >> 6, lane = tid & 63;
  const u16* hr = hs + lane * 402;
  const size_t bs700 = (size_t)lane * 700 + s;

  if (wv == 0) {
    out[OE + bs700] = 1.f / (1.f + expf(dot1(hr, Wh, bh[0])));
    float pl[20];
#pragma unroll
    for (int op = 0; op < 10; ++op) {
      float r0, r1;
      dot2(hr, Wh + (size_t)(1 + 2 * op) * 400, Wh + (size_t)(2 + 2 * op) * 400,
           bh[1 + 2 * op], bh[2 + 2 * op], r0, r1);
      pl[2 * op] = r0; pl[2 * op + 1] = r1;
    }
    float mx = pl[0];
#pragma unroll
    for (int i = 1; i < 20; ++i) mx = fmaxf(mx, pl[i]);
    float sm = 0.f;
#pragma unroll
    for (int i = 0; i < 20; ++i) { pl[i] = expf(pl[i] - mx); sm += pl[i]; }
    const float inv = 1.f / sm;
    float* po = out + OPI + bs700 * 20;
#pragma unroll
    for (int i = 0; i < 20; ++i) po[i] = pl[i] * inv;
  } else if (wv == 1) {
    for (int op = 0; op < 20; ++op) {
      float r0, r1;
      dot2(hr, Wh + (size_t)(21 + 2 * op) * 400, Wh + (size_t)(22 + 2 * op) * 400,
           bh[21 + 2 * op], bh[22 + 2 * op], r0, r1);
      const int o0 = 2 * op, o1 = o0 + 1;
      out[(o0 < 20) ? (OMU1 + bs700 * 20 + o0) : (OMU2 + bs700 * 20 + o0 - 20)] = r0;
      out[(o1 < 20) ? (OMU1 + bs700 * 20 + o1) : (OMU2 + bs700 * 20 + o1 - 20)] = r1;
    }
  } else if (wv == 2) {
    for (int op = 0; op < 20; ++op) {
      float r0, r1;
      dot2(hr, Wh + (size_t)(61 + 2 * op) * 400, Wh + (size_t)(62 + 2 * op) * 400,
           bh[61 + 2 * op], bh[62 + 2 * op], r0, r1);
      const int o0 = 2 * op, o1 = o0 + 1;
      out[(o0 < 20) ? (OSG1 + bs700 * 20 + o0) : (OSG2 + bs700 * 20 + o0 - 20)] = expf(r0);
      out[(o1 < 20) ? (OSG1 + bs700 * 20 + o1) : (OSG2 + bs700 * 20 + o1 - 20)] = expf(r1);
    }
  } else {
    for (int op = 0; op < 10; ++op) {
      float r0, r1;
      dot2(hr, Wh + (size_t)(101 + 2 * op) * 400, Wh + (size_t)(102 + 2 * op) * 400,
           bh[101 + 2 * op], bh[102 + 2 * op], r0, r1);
      float* po = out + ORO + bs700 * 20;
      po[2 * op] = tanhf(r0); po[2 * op + 1] = tanhf(r1);
    }
  }
}

// ---------------- launch ----------------
extern "C" void kernel_launch(void* const* d_in, const int* in_sizes, int n_in,
                              void* d_out, int out_size, void* d_ws, size_t ws_size,
                              hipStream_t stream)
{
  Ptrs in;
  for (int i = 0; i < 33; ++i) in.p[i] = (const float*)d_in[i];
  float* ws  = (float*)d_ws;
  float* out = (float*)d_out;

  hipLaunchKernelGGL(setup_kernel, dim3(4096), dim3(256), 0, stream, in, ws);
  hipLaunchKernelGGL(lstm_scan, dim3(NWG), dim3(512), 0, stream, in, ws, out);
  hipLaunchKernelGGL(heads_kernel, dim3(SS), dim3(256), 0, stream, (const float*)ws, out);
}

// Round 18
// 5137.293 us; speedup vs baseline: 1.8147x; 1.0013x over previous
//
#include <hip/hip_runtime.h>

typedef unsigned short u16;
typedef unsigned int   u32;
typedef unsigned long long u64;
typedef __attribute__((ext_vector_type(8))) _Float16 f16x8;
typedef __attribute__((ext_vector_type(4))) float    f32x4;

constexpr int SS  = 700;
constexpr int NWG = 39;    // 13 WGs per layer; each WG: 32 j x 64 b

// ---- workspace layout (float offsets) ----
constexpr size_t OA1  = 0;        // A-pack L1 [13 jb][8 wv][13 kt][64 lane][8] f16
constexpr size_t OA2  = 346112;   // A-pack L2 [13][8][25][64][8] f16
constexpr size_t OA3  = 1011712;  // A-pack L3
constexpr size_t OWH  = 1677312;  // head weights (3-block-summed) [121][400] f32
constexpr size_t OBH  = 1725712;  // head biases (pad 128)
constexpr size_t OSBT = 1725840;  // u16 [2 parity][64 b][1200 k]  (h1|h2|h3, f16)
constexpr size_t OBAR = 1802640;  // arrival slots @ +wg*16 (39 x 64B-spaced u32)
constexpr size_t OH3  = 1803696;  // u16 [700 t][64 b][400 j]  (f16)

// ---- output layout (float offsets) ----
constexpr size_t OE   = 0;
constexpr size_t OPI  = 44800;
constexpr size_t OMU1 = 940800;
constexpr size_t OMU2 = 1836800;
constexpr size_t OSG1 = 2732800;
constexpr size_t OSG2 = 3628800;
constexpr size_t ORO  = 4524800;
constexpr size_t OST  = 5420800;

struct Ptrs { const float* p[33]; };

union HU { u16 u; _Float16 h; };

__device__ __forceinline__ u16 f2h(float f) {
  HU c; c.h = (_Float16)f; return c.u;
}
__device__ __forceinline__ float h2f(u16 u) {
  HU c; c.u = u; return (float)c.h;
}

// fast sigmoid/tanh: v_exp_f32 + v_rcp_f32, overflow-safe (rcp(inf)=0)
__device__ __forceinline__ float fsigm(float v) {
  return __builtin_amdgcn_rcpf(1.f + __expf(-v));
}
__device__ __forceinline__ float ftanh(float v) {
  return fmaf(2.f, __builtin_amdgcn_rcpf(1.f + __expf(-2.f * v)), -1.f);
}

__device__ __forceinline__ u32 aload(const u32* p) {
  return __hip_atomic_load(p, __ATOMIC_RELAXED, __HIP_MEMORY_SCOPE_AGENT);
}
__device__ __forceinline__ void astore(u32* p, u32 v) {
  __hip_atomic_store(p, v, __ATOMIC_RELAXED, __HIP_MEMORY_SCOPE_AGENT);
}
__device__ __forceinline__ u64 aload64(const u64* p) {
  return __hip_atomic_load(p, __ATOMIC_RELAXED, __HIP_MEMORY_SCOPE_AGENT);
}

// ---------------- setup: pack MFMA A-fragments, init states ----------------
__device__ __forceinline__ float apack_val(const Ptrs& in, int layer, size_t i, int KT)
{
  const int e = (int)(i & 7); const int lane = (int)((i >> 3) & 63);
  size_t q = i >> 9; const int kt = (int)(q % KT); q /= KT;
  const int wv = (int)(q & 7); const int jb = (int)(q >> 3);
  const int rw = lane & 15; const int g = rw & 3; const int jq = rw >> 2;
  const int j = jb * 32 + wv * 4 + jq;
  if (j >= 400) return 0.f;
  const int grow = g * 400 + j;
  const int kk = kt * 32 + 8 * (lane >> 4) + e;
  if (layer == 0) return (kk < 400) ? in.p[8][(size_t)grow * 400 + kk] : 0.f;
  const float* Wih = (layer == 1) ? in.p[11] : in.p[15];
  const float* Whh = (layer == 1) ? in.p[12] : in.p[16];
  return (kk < 400) ? Wih[(size_t)grow * 403 + 3 + kk]
                    : Whh[(size_t)grow * 400 + (kk - 400)];
}

__global__ __launch_bounds__(256) void setup_kernel(Ptrs in, float* __restrict__ ws)
{
  u16* wsu = (u16*)ws;
  const size_t TOTAL = 3481001;
  for (size_t idx = (size_t)blockIdx.x * 256 + threadIdx.x; idx < TOTAL;
       idx += (size_t)gridDim.x * 256) {
    size_t i = idx;
    if (i < 692224)  { wsu[OA1 * 2 + i] = f2h(apack_val(in, 0, i, 13)); continue; }
    i -= 692224;
    if (i < 1331200) { wsu[OA2 * 2 + i] = f2h(apack_val(in, 1, i, 25)); continue; }
    i -= 1331200;
    if (i < 1331200) { wsu[OA3 * 2 + i] = f2h(apack_val(in, 2, i, 25)); continue; }
    i -= 1331200;
    if (i < 48400) {                         // head weights: sum 3 400-blocks
      const int o = (int)(i / 400), k = (int)(i % 400);
      int src, row;
      if      (o == 0)  { src = 19; row = 0; }
      else if (o < 21)  { src = 21; row = o - 1; }
      else if (o < 41)  { src = 23; row = o - 21; }
      else if (o < 61)  { src = 25; row = o - 41; }
      else if (o < 81)  { src = 27; row = o - 61; }
      else if (o < 101) { src = 29; row = o - 81; }
      else              { src = 31; row = o - 101; }
      const float* W = in.p[src] + (size_t)row * 1200;
      ws[OWH + i] = W[k] + W[400 + k] + W[800 + k];
      continue;
    }
    i -= 48400;
    if (i < 121) {                           // head biases
      const int o = (int)i;
      int src, row;
      if      (o == 0)  { src = 20; row = 0; }
      else if (o < 21)  { src = 22; row = o - 1; }
      else if (o < 41)  { src = 24; row = o - 21; }
      else if (o < 61)  { src = 26; row = o - 41; }
      else if (o < 81)  { src = 28; row = o - 61; }
      else if (o < 101) { src = 30; row = o - 81; }
      else              { src = 32; row = o - 101; }
      ws[OBH + i] = in.p[src][row];
      continue;
    }
    i -= 121;
    if (i < 76800) {                         // initial h states -> SBT (f16)
      const int cell = (int)(i / 25600);
      const int rr = (int)(i % 25600);
      const int j = rr >> 6, b = rr & 63;
      const int par = (cell == 1) ? 0 : 1;   // h1->p1, h2->p0, h3->p1
      wsu[OSBT * 2 + (size_t)par * 76800 + (size_t)b * 1200 + cell * 400 + j] =
          f2h(in.p[1 + cell * 2][(size_t)b * 400 + j]);
      continue;
    }
    i -= 76800;
    if (i < 1056) ((u32*)(ws + OBAR))[i] = 0u;
  }
}

// -------- grid barrier: zero-RMW, direct all-poll (single hop), monotone --------
// Arrival: each WG STORES tick n+1 to its own slot (no RMW -> no convoys).
// Wait: EVERY WG's wave 0 gather-polls all 39 slots directly (lane i -> slot i,
// lanes >=39 duplicate slot 0 via same-address broadcast; s_sleep backoff).
// Removes the R16 master->gen second hop: last-arrival -> own detect is 1 poll
// granularity + 1 RT. Per line: 39 4B reads per backoff window (~10x below the
// staging rate). Monotone values, no resets, no HW fences (data path is
// MALL-bypass atomics; __syncthreads drains vmcnt before the arrival store).
__device__ __forceinline__ void grid_barrier(u32* bar, int n)
{
  __syncthreads();                       // drains publish stores of all waves
  if (threadIdx.x == 0)
    astore(bar + (size_t)blockIdx.x * 16, (u32)(n + 1));
  if (threadIdx.x < 64) {
    const int idx = ((int)threadIdx.x < NWG) ? (int)threadIdx.x : 0;
    const u32* cp = bar + (size_t)idx * 16;
    while (__ballot(aload(cp) >= (u32)(n + 1)) != ~0ull)
      __builtin_amdgcn_s_sleep(1);
    __atomic_signal_fence(__ATOMIC_SEQ_CST);
  }
  __syncthreads();
}

// ---------------- scan body ----------------
template<int LAYER>
__device__ __forceinline__ void scan_body(Ptrs in, float* __restrict__ ws,
                                          float* __restrict__ out, char* __restrict__ lds,
                                          u16 (*hstage)[32])
{
  constexpr int KT   = (LAYER == 0) ? 13 : 25;     // K tiles of 32 (L1 padded 400->416)
  constexpr int RB   = KT * 64 + 16;               // LDS row bytes (+8 f16 pad)
  constexpr int CH   = KT * 8;                     // u64 chunks per row (104 / 200)
  constexpr int COL0 = (LAYER == 2) ? 400 : 0;     // SBT col origin (f16 idx)
  constexpr int WCOL = LAYER * 400;                // write col base
  constexpr size_t OA = (LAYER == 0) ? OA1 : ((LAYER == 1) ? OA2 : OA3);

  const int jb   = (int)blockIdx.x - 13 * LAYER;
  const int tid  = (int)threadIdx.x;
  const int lane = tid & 63;
  const int wv   = tid >> 6;          // 0..7 : j-quad owner
  const int jq   = lane >> 4;         // 0..3
  const int bcol = lane & 15;

  u16* SBT = (u16*)(ws + OSBT);
  u16* H3  = (u16*)(ws + OH3);
  u32* bar = (u32*)(ws + OBAR);
  const float* x = in.p[0];

  const int j = jb * 32 + wv * 4 + jq;
  const bool jok = (j < 400);

  // finalize constants (per-lane)
  float xw[12], bias[4], cr[4];
  {
    const float* Wx = (LAYER == 0) ? in.p[7]  : ((LAYER == 1) ? in.p[11] : in.p[15]);
    const int    xs = (LAYER == 0) ? 3 : 403;
    const float* b0 = (LAYER == 0) ? in.p[9]  : ((LAYER == 1) ? in.p[13] : in.p[17]);
    const float* b1 = (LAYER == 0) ? in.p[10] : ((LAYER == 1) ? in.p[14] : in.p[18]);
    const float* ci = (LAYER == 0) ? in.p[2]  : ((LAYER == 1) ? in.p[4]  : in.p[6]);
#pragma unroll
    for (int g = 0; g < 4; ++g) {
      const int grow = g * 400 + j;
#pragma unroll
      for (int dk = 0; dk < 3; ++dk)
        xw[g * 3 + dk] = jok ? Wx[(size_t)grow * xs + dk] : 0.f;
      bias[g] = jok ? (b0[grow] + b1[grow]) : 0.f;
    }
#pragma unroll
    for (int bt = 0; bt < 4; ++bt)
      cr[bt] = jok ? ci[(size_t)(bt * 16 + bcol) * 400 + j] : 0.f;
  }

  // A-fragments (weights) -> registers, resident for the whole scan
  f16x8 A[KT];
  {
    const u16* ap = (u16*)ws + OA * 2 + ((size_t)(jb * 8 + wv) * KT * 64 + lane) * 8;
#pragma unroll
    for (int kt = 0; kt < KT; ++kt)
      A[kt] = *(const f16x8*)(ap + (size_t)kt * 512);
  }

  // hoisted staging offsets (loop-invariant; statically indexed -> registers)
  u32 soff[KT], loff[KT];
#pragma unroll
  for (int i = 0; i < KT; ++i) {
    const int c = tid + i * 512;
    soff[i] = (u32)((c / CH) * 300 + (c % CH));          // u64 units in SBT row space
    loff[i] = (u32)((c / CH) * RB + (c % CH) * 8);       // bytes in LDS
  }

  for (int n = 0; n < 702; ++n) {
    const int p = n & 1;
    const int t = n - LAYER;
    const bool active = (t >= 0) && (t < SS);
    float xv[12];
    if (active) {
#pragma unroll
      for (int bt = 0; bt < 4; ++bt) {
        const float* xp = x + (size_t)t * 192 + (bt * 16 + bcol) * 3;
        xv[bt * 3] = xp[0]; xv[bt * 3 + 1] = xp[1]; xv[bt * 3 + 2] = xp[2];
      }
      // stage h: MALL-bypass u64 atomic loads -> LDS, software-pipelined rounds of 5
      // (<=10 outstanding: below measured congestion knee)
      const u64* src = (const u64*)(SBT + (size_t)(p ^ 1) * 76800 + COL0);
      u64 ta[5], tb[5];
      if constexpr (KT == 25) {
#pragma unroll
        for (int i = 0; i < 5; ++i) ta[i] = aload64(src + soff[i]);
#pragma unroll
        for (int i = 0; i < 5; ++i) tb[i] = aload64(src + soff[5 + i]);
#pragma unroll
        for (int i = 0; i < 5; ++i) *(u64*)(lds + loff[i]) = ta[i];
#pragma unroll
        for (int i = 0; i < 5; ++i) ta[i] = aload64(src + soff[10 + i]);
#pragma unroll
        for (int i = 0; i < 5; ++i) *(u64*)(lds + loff[5 + i]) = tb[i];
#pragma unroll
        for (int i = 0; i < 5; ++i) tb[i] = aload64(src + soff[15 + i]);
#pragma unroll
        for (int i = 0; i < 5; ++i) *(u64*)(lds + loff[10 + i]) = ta[i];
#pragma unroll
        for (int i = 0; i < 5; ++i) ta[i] = aload64(src + soff[20 + i]);
#pragma unroll
        for (int i = 0; i < 5; ++i) *(u64*)(lds + loff[15 + i]) = tb[i];
#pragma unroll
        for (int i = 0; i < 5; ++i) *(u64*)(lds + loff[20 + i]) = ta[i];
      } else {   // KT == 13: rounds 5 + 5 + 3
#pragma unroll
        for (int i = 0; i < 5; ++i) ta[i] = aload64(src + soff[i]);
#pragma unroll
        for (int i = 0; i < 5; ++i) tb[i] = aload64(src + soff[5 + i]);
#pragma unroll
        for (int i = 0; i < 5; ++i) *(u64*)(lds + loff[i]) = ta[i];
#pragma unroll
        for (int i = 0; i < 3; ++i) ta[i] = aload64(src + soff[10 + i]);
#pragma unroll
        for (int i = 0; i < 5; ++i) *(u64*)(lds + loff[5 + i]) = tb[i];
#pragma unroll
        for (int i = 0; i < 3; ++i) *(u64*)(lds + loff[10 + i]) = ta[i];
      }
    }
    __syncthreads();
    if (active) {
      f32x4 acc[4];
#pragma unroll
      for (int bt = 0; bt < 4; ++bt) acc[bt] = (f32x4){0.f, 0.f, 0.f, 0.f};
#pragma unroll
      for (int kt = 0; kt < KT; ++kt) {
#pragma unroll
        for (int bt = 0; bt < 4; ++bt) {
          const f16x8 bv = *(const f16x8*)(lds + (size_t)(bt * 16 + bcol) * RB
                                               + jq * 16 + kt * 64);
          acc[bt] = __builtin_amdgcn_mfma_f32_16x16x32_f16(A[kt], bv, acc[bt], 0, 0, 0);
        }
      }
      if (jok) {
#pragma unroll
        for (int bt = 0; bt < 4; ++bt) {
          const int b = bt * 16 + bcol;
          float gv[4];
#pragma unroll
          for (int g = 0; g < 4; ++g)
            gv[g] = acc[bt][g] + bias[g] + xv[bt * 3] * xw[g * 3]
                  + xv[bt * 3 + 1] * xw[g * 3 + 1] + xv[bt * 3 + 2] * xw[g * 3 + 2];
          const float fi = fsigm(gv[0]), ff = fsigm(gv[1]);
          const float gg = ftanh(gv[2]), oo = fsigm(gv[3]);
          const float cn = ff * cr[bt] + fi * gg;
          const float hn = oo * ftanh(cn);
          cr[bt] = cn;
          hstage[b][wv * 4 + jq] = f2h(hn);             // pack via LDS (contiguous publish)
          if (LAYER == 2) H3[((size_t)t * 64 + b) * 400 + j] = f2h(hn);
          if (t == SS - 1) {
            out[OST + (size_t)(LAYER * 2) * 25600     + (size_t)b * 400 + j] = hn;
            out[OST + (size_t)(LAYER * 2 + 1) * 25600 + (size_t)b * 400 + j] = cn;
          }
        }
      }
    }
    __syncthreads();
    if (active) {
      // publish h-slice: 2 MALL-bypass u32 atomic stores per thread (2 f16 each),
      // consecutive threads -> consecutive dwords (contiguous 64B runs per b-row)
      const u32* hs32 = (const u32*)hstage;
      for (int c = tid; c < 1024; c += 512) {
        const int b = c >> 4, jp = c & 15;
        if (jb * 32 + jp * 2 < 400)
          __hip_atomic_store((u32*)SBT + (size_t)p * 38400 + (size_t)b * 600
                                 + (WCOL + jb * 32) / 2 + jp,
                             hs32[c], __ATOMIC_RELAXED, __HIP_MEMORY_SCOPE_AGENT);
      }
    }
    if (n < 701) grid_barrier(bar, n);
  }
}

// Normal launch: 39 WGs on 256 CUs are always co-resident (1 WG/CU, LDS-limited).
__global__ __launch_bounds__(512, 2) void lstm_scan(Ptrs in, float* __restrict__ ws,
                                                    float* __restrict__ out)
{
  __shared__ __align__(16) char lds[103424];   // 64 rows x 1616 B (L1 uses 54272)
  __shared__ u16 hstage[64][32];               // h repack for paired u32 stores
  if (blockIdx.x < 13)      scan_body<0>(in, ws, out, lds, hstage);
  else if (blockIdx.x < 26) scan_body<1>(in, ws, out, lds, hstage);
  else                      scan_body<2>(in, ws, out, lds, hstage);
}

// ---------------- MDN heads ----------------
__device__ __forceinline__ void dot2(const u16* hr,
    const float* __restrict__ w0p, const float* __restrict__ w1p,
    float b0, float b1, float& r0, float& r1)
{
  float a0 = b0, a1 = b1;
  const float2* W0 = (const float2*)w0p;
  const float2* W1 = (const float2*)w1p;
#pragma unroll 2
  for (int m = 0; m < 200; ++m) {
    const u32 u = *(const u32*)(hr + 2 * m);
    const float lo = h2f((u16)(u & 0xffffu));
    const float hi = h2f((u16)(u >> 16));
    const float2 c0 = W0[m], c1 = W1[m];
    a0 = fmaf(hi, c0.y, fmaf(lo, c0.x, a0));
    a1 = fmaf(hi, c1.y, fmaf(lo, c1.x, a1));
  }
  r0 = a0; r1 = a1;
}

__device__ __forceinline__ float dot1(const u16* hr, const float* __restrict__ w0p, float b0)
{
  float a0 = b0;
  const float2* W0 = (const float2*)w0p;
#pragma unroll 2
  for (int m = 0; m < 200; ++m) {
    const u32 u = *(const u32*)(hr + 2 * m);
    a0 = fmaf(h2f((u16)(u >> 16)),     W0[m].y,
         fmaf(h2f((u16)(u & 0xffffu)), W0[m].x, a0));
  }
  return a0;
}

__global__ __launch_bounds__(256) void heads_kernel(const float* __restrict__ ws,
                                                    float* __restrict__ out)
{
  __shared__ u16 hs[64 * 402];                 // dword stride 201 -> conflict-free
  const u16*  H3 = (const u16*)(ws + OH3);
  const float* Wh = ws + OWH;
  const float* bh = ws + OBH;
  const int s = blockIdx.x;
  const int tid = threadIdx.x;
  {
    const u32* H3r = (const u32*)(H3 + (size_t)s * 25600);   // [b][400 j] rows
    u32* hs32 = (u32*)hs;
    for (int idx = tid; idx < 64 * 200; idx += 256) {
      const int bb = idx / 200, cc = idx % 200;
      hs32[bb * 201 + cc] = H3r[bb * 200 + cc];
    }
  }
  __syncthreads();
  const int wv = tid >> 6, lane = tid & 63;
  const u16* hr = hs + lane * 402;
  const size_t bs700 = (size_t)lane * 700 + s;

  if (wv == 0) {
    out[OE + bs700] = 1.f / (1.f + expf(dot1(hr, Wh, bh[0])));
    float pl[20];
#pragma unroll
    for (int op = 0; op < 10; ++op) {
      float r0, r1;
      dot2(hr, Wh + (size_t)(1 + 2 * op) * 400, Wh + (size_t)(2 + 2 * op) * 400,
           bh[1 + 2 * op], bh[2 + 2 * op], r0, r1);
      pl[2 * op] = r0; pl[2 * op + 1] = r1;
    }
    float mx = pl[0];
#pragma unroll
    for (int i = 1; i < 20; ++i) mx = fmaxf(mx, pl[i]);
    float sm = 0.f;
#pragma unroll
    for (int i = 0; i < 20; ++i) { pl[i] = expf(pl[i] - mx); sm += pl[i]; }
    const float inv = 1.f / sm;
    float* po = out + OPI + bs700 * 20;
#pragma unroll
    for (int i = 0; i < 20; ++i) po[i] = pl[i] * inv;
  } else if (wv == 1) {
    for (int op = 0; op < 20; ++op) {
      float r0, r1;
      dot2(hr, Wh + (size_t)(21 + 2 * op) * 400, Wh + (size_t)(22 + 2 * op) * 400,
           bh[21 + 2 * op], bh[22 + 2 * op], r0, r1);
      const int o0 = 2 * op, o1 = o0 + 1;
      out[(o0 < 20) ? (OMU1 + bs700 * 20 + o0) : (OMU2 + bs700 * 20 + o0 - 20)] = r0;
      out[(o1 < 20) ? (OMU1 + bs700 * 20 + o1) : (OMU2 + bs700 * 20 + o1 - 20)] = r1;
    }
  } else if (wv == 2) {
    for (int op = 0; op < 20; ++op) {
      float r0, r1;
      dot2(hr, Wh + (size_t)(61 + 2 * op) * 400, Wh + (size_t)(62 + 2 * op) * 400,
           bh[61 + 2 * op], bh[62 + 2 * op], r0, r1);
      const int o0 = 2 * op, o1 = o0 + 1;
      out[(o0 < 20) ? (OSG1 + bs700 * 20 + o0) : (OSG2 + bs700 * 20 + o0 - 20)] = expf(r0);
      out[(o1 < 20) ? (OSG1 + bs700 * 20 + o1) : (OSG2 + bs700 * 20 + o1 - 20)] = expf(r1);
    }
  } else {
    for (int op = 0; op < 10; ++op) {
      float r0, r1;
      dot2(hr, Wh + (size_t)(101 + 2 * op) * 400, Wh + (size_t)(102 + 2 * op) * 400,
           bh[101 + 2 * op], bh[102 + 2 * op], r0, r1);
      float* po = out + ORO + bs700 * 20;
      po[2 * op] = tanhf(r0); po[2 * op + 1] = tanhf(r1);
    }
  }
}

// ---------------- launch ----------------
extern "C" void kernel_launch(void* const* d_in, const int* in_sizes, int n_in,
                              void* d_out, int out_size, void* d_ws, size_t ws_size,
                              hipStream_t stream)
{
  Ptrs in;
  for (int i = 0; i < 33; ++i) in.p[i] = (const float*)d_in[i];
  float* ws  = (float*)d_ws;
  float* out = (float*)d_out;

  hipLaunchKernelGGL(setup_kernel, dim3(4096), dim3(256), 0, stream, in, ws);
  hipLaunchKernelGGL(lstm_scan, dim3(NWG), dim3(512), 0, stream, in, ws, out);
  hipLaunchKernelGGL(heads_kernel, dim3(SS), dim3(256), 0, stream, (const float*)ws, out);
}

// Round 20
// 5089.227 us; speedup vs baseline: 1.8319x; 1.0094x over previous
//
#include <hip/hip_runtime.h>

typedef unsigned short u16;
typedef unsigned int   u32;
typedef unsigned long long u64;
typedef __attribute__((ext_vector_type(8))) _Float16 f16x8;
typedef __attribute__((ext_vector_type(4))) float    f32x4;

constexpr int SS  = 700;
constexpr int NWG = 39;    // 13 WGs per layer; each WG: 32 j x 64 b

// ---- workspace layout (float offsets) ----
constexpr size_t OA1  = 0;        // A-pack L1 [13 jb][8 wv][13 kt][64 lane][8] f16
constexpr size_t OA2  = 346112;   // A-pack L2 [13][8][25][64][8] f16
constexpr size_t OA3  = 1011712;  // A-pack L3
constexpr size_t OWH  = 1677312;  // head weights (3-block-summed) [121][400] f32
constexpr size_t OBH  = 1725712;  // head biases (pad 128)
constexpr size_t OSBT = 1725840;  // u16 [2 parity][64 b][1200 k]  (h1|h2|h3, f16)
constexpr size_t OBAR = 1802640;  // arrival slots @ +wg*16 (39 x 64B-spaced u32)
constexpr size_t OH3  = 1803696;  // u16 [700 t][64 b][400 j]  (f16)

// ---- output layout (float offsets) ----
constexpr size_t OE   = 0;
constexpr size_t OPI  = 44800;
constexpr size_t OMU1 = 940800;
constexpr size_t OMU2 = 1836800;
constexpr size_t OSG1 = 2732800;
constexpr size_t OSG2 = 3628800;
constexpr size_t ORO  = 4524800;
constexpr size_t OST  = 5420800;

struct Ptrs { const float* p[33]; };

union HU { u16 u; _Float16 h; };

__device__ __forceinline__ u16 f2h(float f) {
  HU c; c.h = (_Float16)f; return c.u;
}
__device__ __forceinline__ float h2f(u16 u) {
  HU c; c.u = u; return (float)c.h;
}

// fast sigmoid/tanh: v_exp_f32 + v_rcp_f32, overflow-safe (rcp(inf)=0)
__device__ __forceinline__ float fsigm(float v) {
  return __builtin_amdgcn_rcpf(1.f + __expf(-v));
}
__device__ __forceinline__ float ftanh(float v) {
  return fmaf(2.f, __builtin_amdgcn_rcpf(1.f + __expf(-2.f * v)), -1.f);
}

__device__ __forceinline__ u32 aload(const u32* p) {
  return __hip_atomic_load(p, __ATOMIC_RELAXED, __HIP_MEMORY_SCOPE_AGENT);
}
__device__ __forceinline__ void astore(u32* p, u32 v) {
  __hip_atomic_store(p, v, __ATOMIC_RELAXED, __HIP_MEMORY_SCOPE_AGENT);
}
__device__ __forceinline__ u64 aload64(const u64* p) {
  return __hip_atomic_load(p, __ATOMIC_RELAXED, __HIP_MEMORY_SCOPE_AGENT);
}
__device__ __forceinline__ void astore64(u64* p, u64 v) {
  __hip_atomic_store(p, v, __ATOMIC_RELAXED, __HIP_MEMORY_SCOPE_AGENT);
}

// ---------------- setup: pack MFMA A-fragments, init states ----------------
__device__ __forceinline__ float apack_val(const Ptrs& in, int layer, size_t i, int KT)
{
  const int e = (int)(i & 7); const int lane = (int)((i >> 3) & 63);
  size_t q = i >> 9; const int kt = (int)(q % KT); q /= KT;
  const int wv = (int)(q & 7); const int jb = (int)(q >> 3);
  const int rw = lane & 15; const int g = rw & 3; const int jq = rw >> 2;
  const int j = jb * 32 + wv * 4 + jq;
  if (j >= 400) return 0.f;
  const int grow = g * 400 + j;
  const int kk = kt * 32 + 8 * (lane >> 4) + e;
  if (layer == 0) return (kk < 400) ? in.p[8][(size_t)grow * 400 + kk] : 0.f;
  const float* Wih = (layer == 1) ? in.p[11] : in.p[15];
  const float* Whh = (layer == 1) ? in.p[12] : in.p[16];
  return (kk < 400) ? Wih[(size_t)grow * 403 + 3 + kk]
                    : Whh[(size_t)grow * 400 + (kk - 400)];
}

__global__ __launch_bounds__(256) void setup_kernel(Ptrs in, float* __restrict__ ws)
{
  u16* wsu = (u16*)ws;
  const size_t TOTAL = 3481001;
  for (size_t idx = (size_t)blockIdx.x * 256 + threadIdx.x; idx < TOTAL;
       idx += (size_t)gridDim.x * 256) {
    size_t i = idx;
    if (i < 692224)  { wsu[OA1 * 2 + i] = f2h(apack_val(in, 0, i, 13)); continue; }
    i -= 692224;
    if (i < 1331200) { wsu[OA2 * 2 + i] = f2h(apack_val(in, 1, i, 25)); continue; }
    i -= 1331200;
    if (i < 1331200) { wsu[OA3 * 2 + i] = f2h(apack_val(in, 2, i, 25)); continue; }
    i -= 1331200;
    if (i < 48400) {                         // head weights: sum 3 400-blocks
      const int o = (int)(i / 400), k = (int)(i % 400);
      int src, row;
      if      (o == 0)  { src = 19; row = 0; }
      else if (o < 21)  { src = 21; row = o - 1; }
      else if (o < 41)  { src = 23; row = o - 21; }
      else if (o < 61)  { src = 25; row = o - 41; }
      else if (o < 81)  { src = 27; row = o - 61; }
      else if (o < 101) { src = 29; row = o - 81; }
      else              { src = 31; row = o - 101; }
      const float* W = in.p[src] + (size_t)row * 1200;
      ws[OWH + i] = W[k] + W[400 + k] + W[800 + k];
      continue;
    }
    i -= 48400;
    if (i < 121) {                           // head biases
      const int o = (int)i;
      int src, row;
      if      (o == 0)  { src = 20; row = 0; }
      else if (o < 21)  { src = 22; row = o - 1; }
      else if (o < 41)  { src = 24; row = o - 21; }
      else if (o < 61)  { src = 26; row = o - 41; }
      else if (o < 81)  { src = 28; row = o - 61; }
      else if (o < 101) { src = 30; row = o - 81; }
      else              { src = 32; row = o - 101; }
      ws[OBH + i] = in.p[src][row];
      continue;
    }
    i -= 121;
    if (i < 76800) {                         // initial h states -> SBT (f16)
      const int cell = (int)(i / 25600);
      const int rr = (int)(i % 25600);
      const int j = rr >> 6, b = rr & 63;
      const int par = (cell == 1) ? 0 : 1;   // h1->p1, h2->p0, h3->p1
      wsu[OSBT * 2 + (size_t)par * 76800 + (size_t)b * 1200 + cell * 400 + j] =
          f2h(in.p[1 + cell * 2][(size_t)b * 400 + j]);
      continue;
    }
    i -= 76800;
    if (i < 1056) ((u32*)(ws + OBAR))[i] = 0u;
  }
}

// -------- grid barrier: zero-RMW, direct all-poll (single hop), monotone --------
// Arrival: each WG STORES tick n+1 to its own slot (no RMW -> no convoys).
// Wait: EVERY WG's wave 0 gather-polls all 39 slots directly (lane i -> slot i,
// lanes >=39 duplicate slot 0 via same-address broadcast; s_sleep backoff).
// Monotone values, no resets, no HW fences (data path is MALL-bypass atomics;
// __syncthreads drains vmcnt before the arrival store). Measured: tick 7.0 us,
// variance <0.5% (R18).
__device__ __forceinline__ void grid_barrier(u32* bar, int n)
{
  __syncthreads();                       // drains publish stores of all waves
  if (threadIdx.x == 0)
    astore(bar + (size_t)blockIdx.x * 16, (u32)(n + 1));
  if (threadIdx.x < 64) {
    const int idx = ((int)threadIdx.x < NWG) ? (int)threadIdx.x : 0;
    const u32* cp = bar + (size_t)idx * 16;
    while (__ballot(aload(cp) >= (u32)(n + 1)) != ~0ull)
      __builtin_amdgcn_s_sleep(1);
    __atomic_signal_fence(__ATOMIC_SEQ_CST);
  }
  __syncthreads();
}

// ---------------- scan body ----------------
template<int LAYER>
__device__ __forceinline__ void scan_body(Ptrs in, float* __restrict__ ws,
                                          float* __restrict__ out, char* __restrict__ lds,
                                          u16 (*hstage)[32])
{
  constexpr int KT   = (LAYER == 0) ? 13 : 25;     // K tiles of 32 (L1 padded 400->416)
  constexpr int RB   = KT * 64 + 16;               // LDS row bytes (+8 f16 pad)
  constexpr int CH   = KT * 8;                     // u64 chunks per row (104 / 200)
  constexpr int COL0 = (LAYER == 2) ? 400 : 0;     // SBT col origin (f16 idx)
  constexpr int WCOL = LAYER * 400;                // write col base
  constexpr size_t OA = (LAYER == 0) ? OA1 : ((LAYER == 1) ? OA2 : OA3);

  const int jb   = (int)blockIdx.x - 13 * LAYER;
  const int tid  = (int)threadIdx.x;
  const int lane = tid & 63;
  const int wv   = tid >> 6;          // 0..7 : j-quad owner
  const int jq   = lane >> 4;         // 0..3
  const int bcol = lane & 15;

  u16* SBT = (u16*)(ws + OSBT);
  u32* bar = (u32*)(ws + OBAR);
  const float* x = in.p[0];

  const int j = jb * 32 + wv * 4 + jq;
  const bool jok = (j < 400);

  // finalize constants (per-lane)
  float xw[12], bias[4], cr[4];
  {
    const float* Wx = (LAYER == 0) ? in.p[7]  : ((LAYER == 1) ? in.p[11] : in.p[15]);
    const int    xs = (LAYER == 0) ? 3 : 403;
    const float* b0 = (LAYER == 0) ? in.p[9]  : ((LAYER == 1) ? in.p[13] : in.p[17]);
    const float* b1 = (LAYER == 0) ? in.p[10] : ((LAYER == 1) ? in.p[14] : in.p[18]);
    const float* ci = (LAYER == 0) ? in.p[2]  : ((LAYER == 1) ? in.p[4]  : in.p[6]);
#pragma unroll
    for (int g = 0; g < 4; ++g) {
      const int grow = g * 400 + j;
#pragma unroll
      for (int dk = 0; dk < 3; ++dk)
        xw[g * 3 + dk] = jok ? Wx[(size_t)grow * xs + dk] : 0.f;
      bias[g] = jok ? (b0[grow] + b1[grow]) : 0.f;
    }
#pragma unroll
    for (int bt = 0; bt < 4; ++bt)
      cr[bt] = jok ? ci[(size_t)(bt * 16 + bcol) * 400 + j] : 0.f;
  }

  // A-fragments (weights) -> registers, resident for the whole scan
  f16x8 A[KT];
  {
    const u16* ap = (u16*)ws + OA * 2 + ((size_t)(jb * 8 + wv) * KT * 64 + lane) * 8;
#pragma unroll
    for (int kt = 0; kt < KT; ++kt)
      A[kt] = *(const f16x8*)(ap + (size_t)kt * 512);
  }

  // hoisted staging offsets (loop-invariant; statically indexed -> registers)
  u32 soff[KT], loff[KT];
#pragma unroll
  for (int i = 0; i < KT; ++i) {
    const int c = tid + i * 512;
    soff[i] = (u32)((c / CH) * 300 + (c % CH));          // u64 units in SBT row space
    loff[i] = (u32)((c / CH) * RB + (c % CH) * 8);       // bytes in LDS
  }
  // publish offsets (u64 view): thread c -> b = c>>3, seg = c&7 (8 u64 per b-row)
  const int pb   = tid >> 3;            // b row this thread publishes
  const int pseg = tid & 7;             // u64 segment within the 32-u16 slice
  const bool pok = (jb * 32 + pseg * 4 < 400);

  for (int n = 0; n < 702; ++n) {
    const int p = n & 1;
    const int t = n - LAYER;
    const bool active = (t >= 0) && (t < SS);
    float xv[12];
    if (active) {
#pragma unroll
      for (int bt = 0; bt < 4; ++bt) {
        const float* xp = x + (size_t)t * 192 + (bt * 16 + bcol) * 3;
        xv[bt * 3] = xp[0]; xv[bt * 3 + 1] = xp[1]; xv[bt * 3 + 2] = xp[2];
      }
      // stage h: MALL-bypass u64 atomic loads -> LDS, software-pipelined rounds of 5
      const u64* src = (const u64*)(SBT + (size_t)(p ^ 1) * 76800 + COL0);
      u64 ta[5], tb[5];
      if constexpr (KT == 25) {
#pragma unroll
        for (int i = 0; i < 5; ++i) ta[i] = aload64(src + soff[i]);
#pragma unroll
        for (int i = 0; i < 5; ++i) tb[i] = aload64(src + soff[5 + i]);
#pragma unroll
        for (int i = 0; i < 5; ++i) *(u64*)(lds + loff[i]) = ta[i];
#pragma unroll
        for (int i = 0; i < 5; ++i) ta[i] = aload64(src + soff[10 + i]);
#pragma unroll
        for (int i = 0; i < 5; ++i) *(u64*)(lds + loff[5 + i]) = tb[i];
#pragma unroll
        for (int i = 0; i < 5; ++i) tb[i] = aload64(src + soff[15 + i]);
#pragma unroll
        for (int i = 0; i < 5; ++i) *(u64*)(lds + loff[10 + i]) = ta[i];
#pragma unroll
        for (int i = 0; i < 5; ++i) ta[i] = aload64(src + soff[20 + i]);
#pragma unroll
        for (int i = 0; i < 5; ++i) *(u64*)(lds + loff[15 + i]) = tb[i];
#pragma unroll
        for (int i = 0; i < 5; ++i) *(u64*)(lds + loff[20 + i]) = ta[i];
      } else {   // KT == 13: rounds 5 + 5 + 3
#pragma unroll
        for (int i = 0; i < 5; ++i) ta[i] = aload64(src + soff[i]);
#pragma unroll
        for (int i = 0; i < 5; ++i) tb[i] = aload64(src + soff[5 + i]);
#pragma unroll
        for (int i = 0; i < 5; ++i) *(u64*)(lds + loff[i]) = ta[i];
#pragma unroll
        for (int i = 0; i < 3; ++i) ta[i] = aload64(src + soff[10 + i]);
#pragma unroll
        for (int i = 0; i < 5; ++i) *(u64*)(lds + loff[5 + i]) = tb[i];
#pragma unroll
        for (int i = 0; i < 3; ++i) *(u64*)(lds + loff[10 + i]) = ta[i];
      }
    }
    __syncthreads();
    if (active) {
      f32x4 acc[4];
#pragma unroll
      for (int bt = 0; bt < 4; ++bt) acc[bt] = (f32x4){0.f, 0.f, 0.f, 0.f};
#pragma unroll
      for (int kt = 0; kt < KT; ++kt) {
#pragma unroll
        for (int bt = 0; bt < 4; ++bt) {
          const f16x8 bv = *(const f16x8*)(lds + (size_t)(bt * 16 + bcol) * RB
                                               + jq * 16 + kt * 64);
          acc[bt] = __builtin_amdgcn_mfma_f32_16x16x32_f16(A[kt], bv, acc[bt], 0, 0, 0);
        }
      }
      if (jok) {
#pragma unroll
        for (int bt = 0; bt < 4; ++bt) {
          const int b = bt * 16 + bcol;
          float gv[4];
#pragma unroll
          for (int g = 0; g < 4; ++g)
            gv[g] = acc[bt][g] + bias[g] + xv[bt * 3] * xw[g * 3]
                  + xv[bt * 3 + 1] * xw[g * 3 + 1] + xv[bt * 3 + 2] * xw[g * 3 + 2];
          const float fi = fsigm(gv[0]), ff = fsigm(gv[1]);
          const float gg = ftanh(gv[2]), oo = fsigm(gv[3]);
          const float cn = ff * cr[bt] + fi * gg;
          const float hn = oo * ftanh(cn);
          cr[bt] = cn;
          hstage[b][wv * 4 + jq] = f2h(hn);             // pack via LDS (contiguous publish)
          if (t == SS - 1) {
            out[OST + (size_t)(LAYER * 2) * 25600     + (size_t)b * 400 + j] = hn;
            out[OST + (size_t)(LAYER * 2 + 1) * 25600 + (size_t)b * 400 + j] = cn;
          }
        }
      }
    }
    __syncthreads();
    if (active && pok) {
      // publish h-slice: ONE contiguous u64 MALL-bypass store per thread
      // (b = tid>>3, seg = tid&7; SBT row = 1200 u16 = 300 u64  <- R19 bug was 150)
      const u64 w = ((const u64*)hstage)[tid];
      astore64((u64*)SBT + (size_t)p * 19200 + (size_t)pb * 300
                   + (WCOL + jb * 32) / 4 + pseg, w);
      if (LAYER == 2)   // H3 [t][b][400j]: row = 400 u16 = 100 u64
        astore64((u64*)((u16*)(ws + OH3)) + ((size_t)t * 64 + pb) * 100
                     + jb * 8 + pseg, w);
    }
    if (n < 701) grid_barrier(bar, n);
  }
}

// Normal launch: 39 WGs on 256 CUs are always co-resident (1 WG/CU, LDS-limited).
__global__ __launch_bounds__(512, 2) void lstm_scan(Ptrs in, float* __restrict__ ws,
                                                    float* __restrict__ out)
{
  __shared__ __align__(16) char lds[103424];   // 64 rows x 1616 B (L1 uses 54272)
  __shared__ __align__(8) u16 hstage[64][32];  // h repack for u64 publishes
  if (blockIdx.x < 13)      scan_body<0>(in, ws, out, lds, hstage);
  else if (blockIdx.x < 26) scan_body<1>(in, ws, out, lds, hstage);
  else                      scan_body<2>(in, ws, out, lds, hstage);
}

// ---------------- MDN heads ----------------
__device__ __forceinline__ void dot2(const u16* hr,
    const float* __restrict__ w0p, const float* __restrict__ w1p,
    float b0, float b1, float& r0, float& r1)
{
  float a0 = b0, a1 = b1;
  const float2* W0 = (const float2*)w0p;
  const float2* W1 = (const float2*)w1p;
#pragma unroll 2
  for (int m = 0; m < 200; ++m) {
    const u32 u = *(const u32*)(hr + 2 * m);
    const float lo = h2f((u16)(u & 0xffffu));
    const float hi = h2f((u16)(u >> 16));
    const float2 c0 = W0[m], c1 = W1[m];
    a0 = fmaf(hi, c0.y, fmaf(lo, c0.x, a0));
    a1 = fmaf(hi, c1.y, fmaf(lo, c1.x, a1));
  }
  r0 = a0; r1 = a1;
}

__device__ __forceinline__ float dot1(const u16* hr, const float* __restrict__ w0p, float b0)
{
  float a0 = b0;
  const float2* W0 = (const float2*)w0p;
#pragma unroll 2
  for (int m = 0; m < 200; ++m) {
    const u32 u = *(const u32*)(hr + 2 * m);
    a0 = fmaf(h2f((u16)(u >> 16)),     W0[m].y,
         fmaf(h2f((u16)(u & 0xffffu)), W0[m].x, a0));
  }
  return a0;
}

__global__ __launch_bounds__(256) void heads_kernel(const float* __restrict__ ws,
                                                    float* __restrict__ out)
{
  __shared__ u16 hs[64 * 402];                 // dword stride 201 -> conflict-free
  const u16*  H3 = (const u16*)(ws + OH3);
  const float* Wh = ws + OWH;
  const float* bh = ws + OBH;
  const int s = blockIdx.x;
  const int tid = threadIdx.x;
  {
    const u32* H3r = (const u32*)(H3 + (size_t)s * 25600);   // [b][400 j] rows
    u32* hs32 = (u32*)hs;
    for (int idx = tid; idx < 64 * 200; idx += 256) {
      const int bb = idx / 200, cc = idx % 200;
      hs32[bb * 201 + cc] = H3r[bb * 200 + cc];
    }
  }
  __syncthreads();
  const int wv = tid >> 6, lane = tid & 63;
  const u16* hr = hs + lane * 402;
  const size_t bs700 = (size_t)lane * 700 + s;

  if (wv == 0) {
    out[OE + bs700] = 1.f / (1.f + expf(dot1(hr, Wh, bh[0])));
    float pl[20];
#pragma unroll
    for (int op = 0; op < 10; ++op) {
      float r0, r1;
      dot2(hr, Wh + (size_t)(1 + 2 * op) * 400, Wh + (size_t)(2 + 2 * op) * 400,
           bh[1 + 2 * op], bh[2 + 2 * op], r0, r1);
      pl[2 * op] = r0; pl[2 * op + 1] = r1;
    }
    float mx = pl[0];
#pragma unroll
    for (int i = 1; i < 20; ++i) mx = fmaxf(mx, pl[i]);
    float sm = 0.f;
#pragma unroll
    for (int i = 0; i < 20; ++i) { pl[i] = expf(pl[i] - mx); sm += pl[i]; }
    const float inv = 1.f / sm;
    float* po = out + OPI + bs700 * 20;
#pragma unroll
    for (int i = 0; i < 20; ++i) po[i] = pl[i] * inv;
  } else if (wv == 1) {
    for (int op = 0; op < 20; ++op) {
      float r0, r1;
      dot2(hr, Wh + (size_t)(21 + 2 * op) * 400, Wh + (size_t)(22 + 2 * op) * 400,
           bh[21 + 2 * op], bh[22 + 2 * op], r0, r1);
      const int o0 = 2 * op, o1 = o0 + 1;
      out[(o0 < 20) ? (OMU1 + bs700 * 20 + o0) : (OMU2 + bs700 * 20 + o0 - 20)] = r0;
      out[(o1 < 20) ? (OMU1 + bs700 * 20 + o1) : (OMU2 + bs700 * 20 + o1 - 20)] = r1;
    }
  } else if (wv == 2) {
    for (int op = 0; op < 20; ++op) {
      float r0, r1;
      dot2(hr, Wh + (size_t)(61 + 2 * op) * 400, Wh + (size_t)(62 + 2 * op) * 400,
           bh[61 + 2 * op], bh[62 + 2 * op], r0, r1);
      const int o0 = 2 * op, o1 = o0 + 1;
      out[(o0 < 20) ? (OSG1 + bs700 * 20 + o0) : (OSG2 + bs700 * 20 + o0 - 20)] = expf(r0);
      out[(o1 < 20) ? (OSG1 + bs700 * 20 + o1) : (OSG2 + bs700 * 20 + o1 - 20)] = expf(r1);
    }
  } else {
    for (int op = 0; op < 10; ++op) {
      float r0, r1;
      dot2(hr, Wh + (size_t)(101 + 2 * op) * 400, Wh + (size_t)(102 + 2 * op) * 400,
           bh[101 + 2 * op], bh[102 + 2 * op], r0, r1);
      float* po = out + ORO + bs700 * 20;
      po[2 * op] = tanhf(r0); po[2 * op + 1] = tanhf(r1);
    }
  }
}

// ---------------- launch ----------------
extern "C" void kernel_launch(void* const* d_in, const int* in_sizes, int n_in,
                              void* d_out, int out_size, void* d_ws, size_t ws_size,
                              hipStream_t stream)
{
  Ptrs in;
  for (int i = 0; i < 33; ++i) in.p[i] = (const float*)d_in[i];
  float* ws  = (float*)d_ws;
  float* out = (float*)d_out;

  hipLaunchKernelGGL(setup_kernel, dim3(4096), dim3(256), 0, stream, in, ws);
  hipLaunchKernelGGL(lstm_scan, dim3(NWG), dim3(512), 0, stream, in, ws, out);
  hipLaunchKernelGGL(heads_kernel, dim3(SS), dim3(256), 0, stream, (const float*)ws, out);
}